// Round 1
// baseline (686.976 us; speedup 1.0000x reference)
//
#include <hip/hip_runtime.h>
#include <hip/hip_bf16.h>
#include <cstddef>

// Problem constants
#define NB 256   // batch
#define RR 32    // rooms
#define WW 8     // room width
#define HH 6     // room height
#define MXY 72   // map extent
#define EMB 6
#define CIN1 16  // 9 + 1 + 6

typedef __bf16 bf16x8 __attribute__((ext_vector_type(8)));
typedef float floatx4 __attribute__((ext_vector_type(4)));

// --- Workspace layout (byte offsets) ---------------------------------------
// conv weight fragments (bf16/short), packed in exact B-frag order
static const size_t B_W1F  = 0;         // 14 ksteps * 4096 B = 57344 (taps>=25 zero)
static const size_t B_W2F  = 57344;     // 18 * 4096 = 73728
static const size_t B_W3F  = 131072;    // 73728 -> ends 204800
static const size_t B_HEAD = 204800;    // fp32 head weights, 122880 floats = 491520 B
//   float offsets inside HEAD:
static const size_t F_WR1T = 0;         // (64,128)    8192
static const size_t F_WR2T = 8192;      // (128,128)  16384
static const size_t F_F1T  = 24576;     // (128,256)  32768
static const size_t F_F2T  = 57344;     // (256,256)  65536 -> 122880 floats
static const size_t B_FEAT = 696320;    // (256,32,64) f32 = 2097152 B
static const size_t B_CHUNK = 2793472;  // per-chunk activation buffers
// per-image bytes: X bf16 5184*16*2=165888 ; Y bf16 5184*64*2=663552 (x2)
static const size_t PERN_BYTES = 165888 + 2 * 663552;  // 1492992

__device__ inline short f2b(float f) {
    unsigned u = __builtin_bit_cast(unsigned, f);
    unsigned r = (u + 0x7fffu + ((u >> 16) & 1u)) >> 16;
    return (short)r;
}
__device__ inline float b2f(short s) {
    unsigned u = ((unsigned)(unsigned short)s) << 16;
    return __builtin_bit_cast(float, u);
}

// ---------------------------------------------------------------------------
// Prep: conv weights fp32 -> bf16 B-fragment order; head weights transposed.
// Fragment order: [kk][ntile][lane][j] ; virtual k = kk*32 + (lane>>4)*8 + j
// oc = ntile*16 + (lane&15) ; (tap, ci) = (k / CIN, k % CIN)
// ---------------------------------------------------------------------------
__global__ void prep_weights(const float* __restrict__ w1, const float* __restrict__ w2,
                             const float* __restrict__ w3, const float* __restrict__ wr1,
                             const float* __restrict__ wr2, const float* __restrict__ wf1,
                             const float* __restrict__ wf2, char* __restrict__ ws)
{
    short* W1F = (short*)(ws + B_W1F);
    short* W2F = (short*)(ws + B_W2F);
    short* W3F = (short*)(ws + B_W3F);
    float* HEAD = (float*)(ws + B_HEAD);

    int idx = blockIdx.x * 256 + threadIdx.x;
    if (idx < 28672) {  // conv1: 14 ksteps (padded), CIN=16, taps 0..24 real
        int j = idx & 7, lane = (idx >> 3) & 63, nt = (idx >> 9) & 3, kk = idx >> 11;
        int k = kk * 32 + (lane >> 4) * 8 + j;
        int oc = nt * 16 + (lane & 15);
        int tap = k >> 4, ci = k & 15;
        float v = (tap < 25) ? w1[(oc * 16 + ci) * 25 + tap] : 0.f;
        W1F[idx] = f2b(v);
        return;
    }
    idx -= 28672;
    if (idx < 36864) {  // conv2: 18 ksteps, CIN=64, 9 taps
        int j = idx & 7, lane = (idx >> 3) & 63, nt = (idx >> 9) & 3, kk = idx >> 11;
        int k = kk * 32 + (lane >> 4) * 8 + j;
        int oc = nt * 16 + (lane & 15);
        int tap = k >> 6, ci = k & 63;
        W2F[idx] = f2b(w2[(oc * 64 + ci) * 9 + tap]);
        return;
    }
    idx -= 36864;
    if (idx < 36864) {  // conv3
        int j = idx & 7, lane = (idx >> 3) & 63, nt = (idx >> 9) & 3, kk = idx >> 11;
        int k = kk * 32 + (lane >> 4) * 8 + j;
        int oc = nt * 16 + (lane & 15);
        int tap = k >> 6, ci = k & 63;
        W3F[idx] = f2b(w3[(oc * 64 + ci) * 9 + tap]);
        return;
    }
    idx -= 36864;
    if (idx < 8192)  { int o = idx & 127, c = idx >> 7; HEAD[F_WR1T + idx] = wr1[o * 64 + c]; return; }
    idx -= 8192;
    if (idx < 16384) { int o = idx & 127, c = idx >> 7; HEAD[F_WR2T + idx] = wr2[o * 128 + c]; return; }
    idx -= 16384;
    if (idx < 32768) { int o = idx & 255, c = idx >> 8; HEAD[F_F1T + idx] = wf1[o * 128 + c]; return; }
    idx -= 32768;
    if (idx < 65536) { int o = idx & 255, c = idx >> 8; HEAD[F_F2T + idx] = wf2[o * 256 + c]; return; }
}

// ---------------------------------------------------------------------------
// Build X (nc, 72, 72, 16) NHWC bf16 — GATHER style: thread = one output
// pixel; loop over 32 rooms with a bounds test, fp32 register accumulate.
// ---------------------------------------------------------------------------
__global__ __launch_bounds__(256) void build_x(const int* __restrict__ pos,
                                               const float* __restrict__ rt,
                                               const float* __restrict__ emb,
                                               short* __restrict__ X, int n0)
{
    const int nl = blockIdx.y;
    const int n = n0 + nl;
    const int p = blockIdx.x * 256 + threadIdx.x;

    __shared__ int s_px[RR], s_py[RR];
    __shared__ float s_emb[RR * EMB];
    if (threadIdx.x < RR) {
        s_px[threadIdx.x] = pos[(n * RR + threadIdx.x) * 2 + 0];
        s_py[threadIdx.x] = pos[(n * RR + threadIdx.x) * 2 + 1];
    }
    for (int i = threadIdx.x; i < RR * EMB; i += 256) s_emb[i] = emb[i];
    __syncthreads();
    if (p >= MXY * MXY) return;

    const int gx = p / MXY, gy = p - (p / MXY) * MXY;

    float acc[16];
#pragma unroll
    for (int c = 0; c < 16; ++c) acc[c] = 0.f;
    acc[9] = 1.f;

    for (int r = 0; r < RR; ++r) {
        int w = gx - s_px[r], h = gy - s_py[r];
        if ((unsigned)w < (unsigned)WW && (unsigned)h < (unsigned)HH) {
            int j = w * HH + h;
            const float* rr = rt + r * 9 * 48;
#pragma unroll
            for (int c = 0; c < 9; ++c) acc[c] += rr[c * 48 + j];
            float m = rr[j];  // channel 0 = room_map
#pragma unroll
            for (int e = 0; e < EMB; ++e) acc[10 + e] += s_emb[r * EMB + e] * m;
        }
    }

    short o[16];
#pragma unroll
    for (int c = 0; c < 16; ++c) o[c] = f2b(acc[c]);
    short* dst = X + ((size_t)nl * (MXY * MXY) + p) * CIN1;
    *reinterpret_cast<uint4*>(dst) = *reinterpret_cast<uint4*>(o);
    *reinterpret_cast<uint4*>(dst + 8) = *reinterpret_cast<uint4*>(o + 8);
}

// ---------------------------------------------------------------------------
// MFMA conv + bias + ReLU, NHWC bf16. Block = 4 waves (256 thr),
// tile 8x24 px x 64 oc. Wave tile: 48 px (3 m-tiles) x 64 oc (4 n-tiles).
//
// Round 9 (occupancy push): all pipes measured 25-30% busy at 36% occupancy
// -> latency-bound, doubly capped: LDS 37.9K -> 4 blocks AND regs
// (48 AGPR acc + 64 arch = 112) -> 4 waves/SIMD. Break both:
//  * SPLIT staging (conv2/3): k-loop consumes channels in 32-wide halves
//    anyway; stage half 0 (even kk) | barrier | restage half 1 (odd kk).
//    LDS 37440 -> 10*26*40*2 = 20800 B (CIP 72->40; stride 80 B = 20 dwords
//    == 20 mod 32 keeps A-reads <=2-way conflicted in each 16-lane phase).
//  * Dropped the manual 2x4 B ping-pong (32 arch VGPRs) -> single per-kstep
//    B frag (16 VGPRs) + __launch_bounds__(256,5): total ~48+50 <= 102,
//    5 waves/SIMD. B L2 latency (~200cy) now covered by TLP (5 waves x
//    12 MFMAs = 240 matrix cycles per round-robin) instead of ping-pong.
// ---------------------------------------------------------------------------
template <int CIN, int K, int NKP, int CIP, bool SPLIT>
__global__ __launch_bounds__(256, 5) void conv_mfma(const short* __restrict__ in,
                                                    const short* __restrict__ wF,
                                                    const float* __restrict__ bias,
                                                    short* __restrict__ out)
{
    constexpr int PAD = K / 2;
    constexpr int TR = 8 + K - 1;
    constexpr int TC = 24 + K - 1;
    constexpr int SCH = SPLIT ? 32 : CIN;   // channels staged per phase
    constexpr int CG = SCH / 8;             // uint4 groups per pixel per phase

    __shared__ __align__(16) short s_in[TR * TC * CIP];

    const int tid = threadIdx.x;
    const int lane = tid & 63;
    const int wv = tid >> 6;       // 0..3: px-group (48 px each)
    const int ml = lane & 15;
    const int q = lane >> 4;
    const int n = blockIdx.y;
    const int x0 = (blockIdx.x / 3) * 8;
    const int y0 = (blockIdx.x % 3) * 24;

    const short* inn = in + (size_t)n * (MXY * MXY) * CIN;

    // --- stage one 32-channel half (or all CIN if !SPLIT) of the halo tile
    auto stage = [&](int h) {
        for (int i = tid; i < TR * TC * CG; i += 256) {
            int cg = i % CG;
            int pix = i / CG;
            int r = pix / TC, c = pix - r * TC;
            int gx = x0 - PAD + r, gy = y0 - PAD + c;
            uint4 v = make_uint4(0u, 0u, 0u, 0u);
            if ((unsigned)gx < (unsigned)MXY && (unsigned)gy < (unsigned)MXY)
                v = *reinterpret_cast<const uint4*>(inn + ((size_t)gx * MXY + gy) * CIN +
                                                    h * 32 + cg * 8);
            *reinterpret_cast<uint4*>(&s_in[pix * CIP + cg * 8]) = v;
        }
    };

    // per-lane pixel coords for A fragments (3 m-tiles of 16 pixels)
    int prow[3], pcol[3];
#pragma unroll
    for (int i = 0; i < 3; ++i) {
        int p = wv * 48 + i * 16 + ml;
        prow[i] = p / 24;
        pcol[i] = p - prow[i] * 24;
    }

    floatx4 acc[3][4] = {};

    // one kstep: load 4 B frags (global, L1/L2-resident weights), 3 A frags
    // (LDS), 12 MFMAs. Full unroll -> A addresses fold to base+immediate.
    auto do_kstep = [&](int kk, int tap, int chb) {
        bf16x8 B[4];
        const short* src = wF + (size_t)kk * 2048;
#pragma unroll
        for (int j2 = 0; j2 < 4; ++j2)
            B[j2] = *reinterpret_cast<const bf16x8*>(src + (j2 * 64 + lane) * 8);
        const int dx = tap / K, dy = tap - (tap / K) * K;
#pragma unroll
        for (int i = 0; i < 3; ++i) {
            bf16x8 A = *reinterpret_cast<const bf16x8*>(
                &s_in[((prow[i] + dx) * TC + (pcol[i] + dy)) * CIP + chb]);
#pragma unroll
            for (int j2 = 0; j2 < 4; ++j2)
                acc[i][j2] = __builtin_amdgcn_mfma_f32_16x16x32_bf16(
                    A, B[j2], acc[i][j2], 0, 0, 0);
        }
    };

    if constexpr (!SPLIT) {
        // conv1: full 16 channels staged once; kstep spans taps 2kk, 2kk+1
        stage(0);
        __syncthreads();
#pragma unroll
        for (int kk = 0; kk < NKP; ++kk) {
            int tap = kk * 2 + (q >> 1);
            if (tap > 24) tap = 24;   // padded tail weights are zero
            do_kstep(kk, tap, (q & 1) * 8);
        }
    } else {
        // conv2/3: half 0 = channels 0..31 (even kk), half 1 = 32..63 (odd kk)
        constexpr int NH = NKP / 2;   // 9 taps
        stage(0);
        __syncthreads();
#pragma unroll
        for (int t = 0; t < NH; ++t) do_kstep(2 * t, t, q * 8);
        __syncthreads();              // all waves done reading half-0 tile
        stage(1);
        __syncthreads();
#pragma unroll
        for (int t = 0; t < NH; ++t) do_kstep(2 * t + 1, t, q * 8);
    }

    // --- epilogue: bias + relu, bf16 NHWC stores ---
    float b4[4];
#pragma unroll
    for (int j2 = 0; j2 < 4; ++j2) b4[j2] = bias[j2 * 16 + ml];

    short* outn = out + (size_t)n * (MXY * MXY) * 64;
#pragma unroll
    for (int i = 0; i < 3; ++i) {
#pragma unroll
        for (int r = 0; r < 4; ++r) {
            int p = wv * 48 + i * 16 + q * 4 + r;
            int row = p / 24, col = p - row * 24;
            size_t base = ((size_t)(x0 + row) * MXY + (y0 + col)) * 64;
#pragma unroll
            for (int j2 = 0; j2 < 4; ++j2) {
                float v = acc[i][j2][r] + b4[j2];
                outn[base + j2 * 16 + ml] = f2b(fmaxf(v, 0.f));
            }
        }
    }
}

// ---------------------------------------------------------------------------
// Masked gather + mean over room footprint: feat[n][r][c] (fp32 out)
// One wave per (room, sample); lane = channel (coalesced bf16 NHWC reads).
// ---------------------------------------------------------------------------
__global__ void gather_mean(const short* __restrict__ Y, const float* __restrict__ rt,
                            const int* __restrict__ pos, float* __restrict__ feat, int n0)
{
    const int r = blockIdx.x;
    const int nl = blockIdx.y;
    const int n = n0 + nl;
    const int c = threadIdx.x;  // 64
    const int px = pos[(n * RR + r) * 2 + 0];
    const int py = pos[(n * RR + r) * 2 + 1];
    const short* y = Y + (size_t)nl * (MXY * MXY) * 64;
    const float* m = rt + r * 9 * 48;   // channel 0 = room_map

    float s = 0.f, ms = 0.f;
    for (int w = 0; w < WW; ++w)
        for (int h = 0; h < HH; ++h) {
            float mv = m[w * HH + h];
            ms += mv;
            if (mv != 0.f)
                s += mv * b2f(y[((size_t)(px + w) * MXY + (py + h)) * 64 + c]);
        }
    feat[((size_t)n * RR + r) * 64 + c] = s / ms;
}

// ---------------------------------------------------------------------------
// Per-sample head: room MLP (64->128->128), room-sum, fc1 (128->256), fc2
// ---------------------------------------------------------------------------
__global__ __launch_bounds__(256) void mlp_head(const float* __restrict__ feat,
                                                const float* __restrict__ HEAD,
                                                const float* __restrict__ b1,
                                                const float* __restrict__ b2,
                                                const float* __restrict__ bf1,
                                                const float* __restrict__ bf2,
                                                float* __restrict__ outp)
{
    __shared__ __align__(16) float s_feat[RR * 64];
    __shared__ __align__(16) float s_h1[RR * 128];
    __shared__ __align__(16) float s_s[2 * 128];
    __shared__ __align__(16) float s_sf[128];
    __shared__ __align__(16) float s_t1[256];

    const int n = blockIdx.x;
    const int tid = threadIdx.x;
    const float* W1t = HEAD + F_WR1T;
    const float* W2t = HEAD + F_WR2T;
    const float* F1t = HEAD + F_F1T;
    const float* F2t = HEAD + F_F2T;

    for (int i = tid; i < RR * 64; i += 256) s_feat[i] = feat[(size_t)n * RR * 64 + i];
    __syncthreads();

    const int o = tid & 127;
    const int rh = tid >> 7;

    float acc[16];
#pragma unroll
    for (int r = 0; r < 16; ++r) acc[r] = b1[o];
    for (int c4 = 0; c4 < 16; ++c4) {
        float w0 = W1t[(c4 * 4 + 0) * 128 + o];
        float w1 = W1t[(c4 * 4 + 1) * 128 + o];
        float w2 = W1t[(c4 * 4 + 2) * 128 + o];
        float w3 = W1t[(c4 * 4 + 3) * 128 + o];
#pragma unroll
        for (int r = 0; r < 16; ++r) {
            float4 f = *reinterpret_cast<const float4*>(&s_feat[(rh * 16 + r) * 64 + c4 * 4]);
            acc[r] += f.x * w0 + f.y * w1 + f.z * w2 + f.w * w3;
        }
    }
#pragma unroll
    for (int r = 0; r < 16; ++r) s_h1[(rh * 16 + r) * 128 + o] = fmaxf(acc[r], 0.f);
    __syncthreads();

#pragma unroll
    for (int r = 0; r < 16; ++r) acc[r] = b2[o];
    for (int c4 = 0; c4 < 32; ++c4) {
        float w0 = W2t[(c4 * 4 + 0) * 128 + o];
        float w1 = W2t[(c4 * 4 + 1) * 128 + o];
        float w2 = W2t[(c4 * 4 + 2) * 128 + o];
        float w3 = W2t[(c4 * 4 + 3) * 128 + o];
#pragma unroll
        for (int r = 0; r < 16; ++r) {
            float4 f = *reinterpret_cast<const float4*>(&s_h1[(rh * 16 + r) * 128 + c4 * 4]);
            acc[r] += f.x * w0 + f.y * w1 + f.z * w2 + f.w * w3;
        }
    }
    float ps = 0.f;
#pragma unroll
    for (int r = 0; r < 16; ++r) ps += fmaxf(acc[r], 0.f);
    s_s[rh * 128 + o] = ps;
    __syncthreads();
    if (tid < 128) s_sf[tid] = s_s[tid] + s_s[128 + tid];
    __syncthreads();

    {
        float a = bf1[tid];
        for (int c4 = 0; c4 < 32; ++c4) {
            float4 f = *reinterpret_cast<const float4*>(&s_sf[c4 * 4]);
            a += f.x * F1t[(c4 * 4 + 0) * 256 + tid];
            a += f.y * F1t[(c4 * 4 + 1) * 256 + tid];
            a += f.z * F1t[(c4 * 4 + 2) * 256 + tid];
            a += f.w * F1t[(c4 * 4 + 3) * 256 + tid];
        }
        s_t1[tid] = fmaxf(a, 0.f);
    }
    __syncthreads();

    {
        float a = bf2[tid];
        for (int c4 = 0; c4 < 64; ++c4) {
            float4 f = *reinterpret_cast<const float4*>(&s_t1[c4 * 4]);
            a += f.x * F2t[(c4 * 4 + 0) * 256 + tid];
            a += f.y * F2t[(c4 * 4 + 1) * 256 + tid];
            a += f.z * F2t[(c4 * 4 + 2) * 256 + tid];
            a += f.w * F2t[(c4 * 4 + 3) * 256 + tid];
        }
        outp[(size_t)n * 256 + tid] = a;
    }
}

// ---------------------------------------------------------------------------
extern "C" void kernel_launch(void* const* d_in, const int* in_sizes, int n_in,
                              void* d_out, int out_size, void* d_ws, size_t ws_size,
                              hipStream_t stream)
{
    const int* pos = (const int*)d_in[0];
    const float* rt = (const float*)d_in[1];
    const float* emb = (const float*)d_in[2];
    const float* w1 = (const float*)d_in[3];
    const float* bc1 = (const float*)d_in[4];
    const float* w2 = (const float*)d_in[5];
    const float* bc2 = (const float*)d_in[6];
    const float* w3 = (const float*)d_in[7];
    const float* bc3 = (const float*)d_in[8];
    const float* wr1 = (const float*)d_in[9];
    const float* br1 = (const float*)d_in[10];
    const float* wr2 = (const float*)d_in[11];
    const float* br2 = (const float*)d_in[12];
    const float* wf1 = (const float*)d_in[13];
    const float* bf1 = (const float*)d_in[14];
    const float* wf2 = (const float*)d_in[15];
    const float* bf2 = (const float*)d_in[16];
    float* out = (float*)d_out;
    char* ws = (char*)d_ws;

    prep_weights<<<880, 256, 0, stream>>>(w1, w2, w3, wr1, wr2, wf1, wf2, ws);

    // pick largest batch chunk that fits the workspace
    int nc = 16;
    const int cands[4] = {256, 128, 64, 32};
    for (int k = 0; k < 4; ++k) {
        size_t need = B_CHUNK + (size_t)cands[k] * PERN_BYTES;
        if (need <= ws_size) { nc = cands[k]; break; }
    }

    short* W1F = (short*)(ws + B_W1F);
    short* W2F = (short*)(ws + B_W2F);
    short* W3F = (short*)(ws + B_W3F);
    float* HEAD = (float*)(ws + B_HEAD);
    float* FEAT = (float*)(ws + B_FEAT);
    short* Xc = (short*)(ws + B_CHUNK);
    short* YA = Xc + (size_t)nc * (MXY * MXY) * CIN1;
    short* YB = YA + (size_t)nc * (MXY * MXY) * 64;

    for (int n0 = 0; n0 < NB; n0 += nc) {
        build_x<<<dim3(21, nc), 256, 0, stream>>>(pos, rt, emb, Xc, n0);
        conv_mfma<16, 5, 14, 24, false><<<dim3(27, nc), 256, 0, stream>>>(Xc, W1F, bc1, YA);
        conv_mfma<64, 3, 18, 40, true><<<dim3(27, nc), 256, 0, stream>>>(YA, W2F, bc2, YB);
        conv_mfma<64, 3, 18, 40, true><<<dim3(27, nc), 256, 0, stream>>>(YB, W3F, bc3, YA);
        gather_mean<<<dim3(RR, nc), 64, 0, stream>>>(YA, rt, pos, FEAT, n0);
    }

    mlp_head<<<NB, 256, 0, stream>>>(FEAT, HEAD, br1, br2, bf1, bf2, out);
}

// Round 2
// 503.526 us; speedup vs baseline: 1.3643x; 1.3643x over previous
//
#include <hip/hip_runtime.h>
#include <hip/hip_bf16.h>
#include <cstddef>

// Problem constants
#define NB 256   // batch
#define RR 32    // rooms
#define WW 8     // room width
#define HH 6     // room height
#define MXY 72   // map extent
#define EMB 6
#define CIN1 16  // 9 + 1 + 6

typedef __bf16 bf16x8 __attribute__((ext_vector_type(8)));
typedef float floatx4 __attribute__((ext_vector_type(4)));

// --- Workspace layout (byte offsets) ---------------------------------------
// conv weight fragments (bf16/short), packed in exact B-frag order
static const size_t B_W1F  = 0;         // 14 ksteps * 4096 B = 57344 (taps>=25 zero)
static const size_t B_W2F  = 57344;     // 18 * 4096 = 73728
static const size_t B_W3F  = 131072;    // 73728 -> ends 204800
static const size_t B_RAUX = 204800;    // room masks (32 u64 = 256B) + inv size (32 f32)
static const size_t B_RINV = 205056;    // 128 B
static const size_t B_HEAD = 205312;    // fp32 head weights, 122880 floats = 491520 B
//   float offsets inside HEAD:
static const size_t F_WR1T = 0;         // (64,128)    8192
static const size_t F_WR2T = 8192;      // (128,128)  16384
static const size_t F_F1T  = 24576;     // (128,256)  32768
static const size_t F_F2T  = 57344;     // (256,256)  65536 -> 122880 floats
static const size_t B_FEAT = 696832;    // (256,32,64) f32 = 2097152 B
static const size_t B_CHUNK = 2793984;  // per-chunk activation buffers
// per-image bytes: X bf16 5184*16*2=165888 ; Y bf16 5184*64*2=663552 (x2)
static const size_t PERN_BYTES = 165888 + 2 * 663552;  // 1492992

__device__ inline short f2b(float f) {
    unsigned u = __builtin_bit_cast(unsigned, f);
    unsigned r = (u + 0x7fffu + ((u >> 16) & 1u)) >> 16;
    return (short)r;
}
__device__ inline float b2f(short s) {
    unsigned u = ((unsigned)(unsigned short)s) << 16;
    return __builtin_bit_cast(float, u);
}

// ---------------------------------------------------------------------------
// Prep: conv weights fp32 -> bf16 B-fragment order; head weights transposed.
// Fragment order: [kk][ntile][lane][j] ; virtual k = kk*32 + (lane>>4)*8 + j
// oc = ntile*16 + (lane&15) ; (tap, ci) = (k / CIN, k % CIN)
// ---------------------------------------------------------------------------
__global__ void prep_weights(const float* __restrict__ w1, const float* __restrict__ w2,
                             const float* __restrict__ w3, const float* __restrict__ wr1,
                             const float* __restrict__ wr2, const float* __restrict__ wf1,
                             const float* __restrict__ wf2, char* __restrict__ ws)
{
    short* W1F = (short*)(ws + B_W1F);
    short* W2F = (short*)(ws + B_W2F);
    short* W3F = (short*)(ws + B_W3F);
    float* HEAD = (float*)(ws + B_HEAD);

    int idx = blockIdx.x * 256 + threadIdx.x;
    if (idx < 28672) {  // conv1: 14 ksteps (padded), CIN=16, taps 0..24 real
        int j = idx & 7, lane = (idx >> 3) & 63, nt = (idx >> 9) & 3, kk = idx >> 11;
        int k = kk * 32 + (lane >> 4) * 8 + j;
        int oc = nt * 16 + (lane & 15);
        int tap = k >> 4, ci = k & 15;
        float v = (tap < 25) ? w1[(oc * 16 + ci) * 25 + tap] : 0.f;
        W1F[idx] = f2b(v);
        return;
    }
    idx -= 28672;
    if (idx < 36864) {  // conv2: 18 ksteps, CIN=64, 9 taps
        int j = idx & 7, lane = (idx >> 3) & 63, nt = (idx >> 9) & 3, kk = idx >> 11;
        int k = kk * 32 + (lane >> 4) * 8 + j;
        int oc = nt * 16 + (lane & 15);
        int tap = k >> 6, ci = k & 63;
        W2F[idx] = f2b(w2[(oc * 64 + ci) * 9 + tap]);
        return;
    }
    idx -= 36864;
    if (idx < 36864) {  // conv3
        int j = idx & 7, lane = (idx >> 3) & 63, nt = (idx >> 9) & 3, kk = idx >> 11;
        int k = kk * 32 + (lane >> 4) * 8 + j;
        int oc = nt * 16 + (lane & 15);
        int tap = k >> 6, ci = k & 63;
        W3F[idx] = f2b(w3[(oc * 64 + ci) * 9 + tap]);
        return;
    }
    idx -= 36864;
    if (idx < 8192)  { int o = idx & 127, c = idx >> 7; HEAD[F_WR1T + idx] = wr1[o * 64 + c]; return; }
    idx -= 8192;
    if (idx < 16384) { int o = idx & 127, c = idx >> 7; HEAD[F_WR2T + idx] = wr2[o * 128 + c]; return; }
    idx -= 16384;
    if (idx < 32768) { int o = idx & 255, c = idx >> 8; HEAD[F_F1T + idx] = wf1[o * 128 + c]; return; }
    idx -= 32768;
    if (idx < 65536) { int o = idx & 255, c = idx >> 8; HEAD[F_F2T + idx] = wf2[o * 256 + c]; return; }
}

// Room footprint bitmasks (48 bits) + 1/room_size, for the fused gather.
__global__ void prep_rooms(const float* __restrict__ rt, char* __restrict__ ws)
{
    int r = threadIdx.x;
    if (r >= RR) return;
    unsigned long long m = 0ull;
    int cnt = 0;
    for (int j = 0; j < WW * HH; ++j)
        if (rt[r * 9 * 48 + j] != 0.f) { m |= (1ull << j); ++cnt; }
    ((unsigned long long*)(ws + B_RAUX))[r] = m;
    ((float*)(ws + B_RINV))[r] = 1.f / (float)cnt;
}

__global__ void zero_feat(float* __restrict__ feat)
{
    feat[(size_t)blockIdx.x * 256 + threadIdx.x] = 0.f;
}

// ---------------------------------------------------------------------------
// Build X (nc, 72, 72, 16) NHWC bf16 — GATHER style: thread = one output
// pixel; loop over 32 rooms with a bounds test, fp32 register accumulate.
// ---------------------------------------------------------------------------
__global__ __launch_bounds__(256) void build_x(const int* __restrict__ pos,
                                               const float* __restrict__ rt,
                                               const float* __restrict__ emb,
                                               short* __restrict__ X, int n0)
{
    const int nl = blockIdx.y;
    const int n = n0 + nl;
    const int p = blockIdx.x * 256 + threadIdx.x;

    __shared__ int s_px[RR], s_py[RR];
    __shared__ float s_emb[RR * EMB];
    if (threadIdx.x < RR) {
        s_px[threadIdx.x] = pos[(n * RR + threadIdx.x) * 2 + 0];
        s_py[threadIdx.x] = pos[(n * RR + threadIdx.x) * 2 + 1];
    }
    for (int i = threadIdx.x; i < RR * EMB; i += 256) s_emb[i] = emb[i];
    __syncthreads();
    if (p >= MXY * MXY) return;

    const int gx = p / MXY, gy = p - (p / MXY) * MXY;

    float acc[16];
#pragma unroll
    for (int c = 0; c < 16; ++c) acc[c] = 0.f;
    acc[9] = 1.f;

    for (int r = 0; r < RR; ++r) {
        int w = gx - s_px[r], h = gy - s_py[r];
        if ((unsigned)w < (unsigned)WW && (unsigned)h < (unsigned)HH) {
            int j = w * HH + h;
            const float* rr = rt + r * 9 * 48;
#pragma unroll
            for (int c = 0; c < 9; ++c) acc[c] += rr[c * 48 + j];
            float m = rr[j];  // channel 0 = room_map
#pragma unroll
            for (int e = 0; e < EMB; ++e) acc[10 + e] += s_emb[r * EMB + e] * m;
        }
    }

    short o[16];
#pragma unroll
    for (int c = 0; c < 16; ++c) o[c] = f2b(acc[c]);
    short* dst = X + ((size_t)nl * (MXY * MXY) + p) * CIN1;
    *reinterpret_cast<uint4*>(dst) = *reinterpret_cast<uint4*>(o);
    *reinterpret_cast<uint4*>(dst + 8) = *reinterpret_cast<uint4*>(o + 8);
}

// ---------------------------------------------------------------------------
// MFMA conv + bias + ReLU, NHWC bf16. Block = 4 waves (256 thr),
// tile 8x24 px x 64 oc. Wave tile: 48 px (3 m-tiles) x 64 oc (4 n-tiles).
// ROUND-0 structure (proven 65us/dispatch): single 64-ch stage (CIP=72,
// LDS 37.9K, 4 blocks/CU), B-frag register ping-pong covering L2 latency.
// Round-1's split-staging experiment tripled FETCH (L2 had evicted the tile
// by the second pass) and regressed 1.6x — do NOT re-split.
//
// FUSE (conv3 only): Y3 is consumed ONLY by the room-mean gather, so skip
// the 83MB/dispatch output write entirely: per block, build the intersecting
// room list (ballot, ~4 rooms avg), accumulate masked per-room channel sums
// from the register accumulators into an LDS slab (reusing s_in), then one
// global fp32 atomicAdd per (room,channel). Mean division happens in
// mlp_head via the precomputed 1/room_size table.
// ---------------------------------------------------------------------------
template <int CIN, int K, int NKP, int CIP, bool FUSE>
__global__ __launch_bounds__(256, 3) void conv_mfma(const short* __restrict__ in,
                                                    const short* __restrict__ wF,
                                                    const float* __restrict__ bias,
                                                    short* __restrict__ out,
                                                    const int* __restrict__ pos,
                                                    const unsigned long long* __restrict__ rmask,
                                                    float* __restrict__ feat, int n0)
{
    constexpr int PAD = K / 2;
    constexpr int TR = 8 + K - 1;
    constexpr int TC = 24 + K - 1;
    constexpr int CG = CIN / 8;

    __shared__ __align__(16) short s_in[TR * TC * CIP];

    const int tid = threadIdx.x;
    const int lane = tid & 63;
    const int wv = tid >> 6;       // 0..3: px-group (48 px each)
    const int ml = lane & 15;
    const int q = lane >> 4;
    const int n = blockIdx.y;
    const int x0 = (blockIdx.x / 3) * 8;
    const int y0 = (blockIdx.x % 3) * 24;

    const short* inn = in + (size_t)n * (MXY * MXY) * CIN;

    // B-fragment register ping-pong: [buf][ntile], one kstep per buffer
    bf16x8 Bbuf[2][4];
    auto load_k = [&](int kk, bf16x8* dst) {
        const short* src = wF + (size_t)kk * 2048;
#pragma unroll
        for (int j2 = 0; j2 < 4; ++j2)
            dst[j2] = *reinterpret_cast<const bf16x8*>(src + (j2 * 64 + lane) * 8);
    };

    load_k(0, Bbuf[0]);

    // --- stage input tile (zero-padded halo), 16B per thread-iteration ---
    for (int i = tid; i < TR * TC * CG; i += 256) {
        int cg = i % CG;
        int pix = i / CG;
        int r = pix / TC, c = pix - r * TC;
        int gx = x0 - PAD + r, gy = y0 - PAD + c;
        uint4 v = make_uint4(0u, 0u, 0u, 0u);
        if ((unsigned)gx < (unsigned)MXY && (unsigned)gy < (unsigned)MXY)
            v = *reinterpret_cast<const uint4*>(inn + ((size_t)gx * MXY + gy) * CIN + cg * 8);
        *reinterpret_cast<uint4*>(&s_in[pix * CIP + cg * 8]) = v;
    }
    __syncthreads();  // the ONLY barrier before the epilogue

    // per-lane pixel coords for A fragments (3 m-tiles of 16 pixels)
    int prow[3], pcol[3];
#pragma unroll
    for (int i = 0; i < 3; ++i) {
        int p = wv * 48 + i * 16 + ml;
        prow[i] = p / 24;
        pcol[i] = p - prow[i] * 24;
    }

    floatx4 acc[3][4] = {};

#pragma unroll
    for (int kk = 0; kk < NKP; ++kk) {
        // prefetch next kstep's B frags into the other buffer (wave-local
        // vmcnt only; 12 MFMAs below cover L2 latency)
        if (kk + 1 < NKP) load_k(kk + 1, Bbuf[(kk + 1) & 1]);

        int tap, chb;
        if (CIN == 16) {  // conv1: kstep spans taps 2kk, 2kk+1 (tap>=25 weights are 0)
            tap = kk * 2 + (q >> 1);
            if (tap > 24) tap = 24;
            chb = (q & 1) * 8;
        } else {          // conv2/3: kstep = half of one tap's 64 channels
            tap = kk >> 1;
            chb = (kk & 1) * 32 + q * 8;
        }
        const int dx = tap / K, dy = tap - dx * K;

#pragma unroll
        for (int i = 0; i < 3; ++i) {
            bf16x8 A = *reinterpret_cast<const bf16x8*>(
                &s_in[((prow[i] + dx) * TC + (pcol[i] + dy)) * CIP + chb]);
#pragma unroll
            for (int j2 = 0; j2 < 4; ++j2)
                acc[i][j2] = __builtin_amdgcn_mfma_f32_16x16x32_bf16(
                    A, Bbuf[kk & 1][j2], acc[i][j2], 0, 0, 0);
        }
    }

    // --- epilogue ---
    float b4[4];
#pragma unroll
    for (int j2 = 0; j2 < 4; ++j2) b4[j2] = bias[j2 * 16 + ml];

    if constexpr (!FUSE) {
        short* outn = out + (size_t)n * (MXY * MXY) * 64;
#pragma unroll
        for (int i = 0; i < 3; ++i) {
#pragma unroll
            for (int r = 0; r < 4; ++r) {
                int p = wv * 48 + i * 16 + q * 4 + r;
                int row = p / 24, col = p - row * 24;
                size_t base = ((size_t)(x0 + row) * MXY + (y0 + col)) * 64;
#pragma unroll
                for (int j2 = 0; j2 < 4; ++j2) {
                    float v = acc[i][j2][r] + b4[j2];
                    outn[base + j2 * 16 + ml] = f2b(fmaxf(v, 0.f));
                }
            }
        }
    } else {
        // bias + relu in place
#pragma unroll
        for (int i = 0; i < 3; ++i)
#pragma unroll
            for (int j2 = 0; j2 < 4; ++j2)
#pragma unroll
                for (int r = 0; r < 4; ++r)
                    acc[i][j2][r] = fmaxf(acc[i][j2][r] + b4[j2], 0.f);

        __syncthreads();  // all A-frag LDS reads done -> reuse s_in as scratch
        char* sc = (char*)s_in;
        float* s_feat = (float*)sc;                                   // 32*64 f32 = 8192 B
        int* s_rl = (int*)(sc + 8192);                                // room ids   (128 B)
        unsigned long long* s_mk = (unsigned long long*)(sc + 8320);  // masks      (256 B)
        int* s_pxy = (int*)(sc + 8576);                               // px,py      (256 B)
        int* s_cnt = (int*)(sc + 8832);

        for (int i = tid; i < RR * 64; i += 256) s_feat[i] = 0.f;
        if (tid < 64) {  // wave 0 builds the intersect list (no atomics)
            int r = lane;
            bool hit = false;
            int rpx = 0, rpy = 0;
            if (r < RR) {
                rpx = pos[((size_t)(n0 + n) * RR + r) * 2 + 0];
                rpy = pos[((size_t)(n0 + n) * RR + r) * 2 + 1];
                hit = (rpx + WW > x0) && (rpx < x0 + 8) &&
                      (rpy + HH > y0) && (rpy < y0 + 24);
            }
            unsigned long long bal = __ballot(hit);
            if (hit) {
                int idx = __popcll(bal & ((1ull << lane) - 1ull));
                s_rl[idx] = r;
                s_pxy[2 * idx] = rpx;
                s_pxy[2 * idx + 1] = rpy;
                s_mk[idx] = rmask[r];
            }
            if (lane == 0) *s_cnt = (int)__popcll(bal);
        }
        __syncthreads();
        const int nr = *s_cnt;

        for (int li = 0; li < nr; ++li) {
            const int rpx = s_pxy[2 * li], rpy = s_pxy[2 * li + 1];
            const unsigned long long mk = s_mk[li];
            float s0 = 0.f, s1 = 0.f, s2 = 0.f, s3 = 0.f;
            bool any = false;
#pragma unroll
            for (int i = 0; i < 3; ++i) {
#pragma unroll
                for (int r = 0; r < 4; ++r) {
                    int p = wv * 48 + i * 16 + q * 4 + r;
                    int row = p / 24, col = p - row * 24;
                    int w = x0 + row - rpx, h = y0 + col - rpy;
                    if ((unsigned)w < (unsigned)WW && (unsigned)h < (unsigned)HH &&
                        ((mk >> (w * HH + h)) & 1ull)) {
                        s0 += acc[i][0][r];
                        s1 += acc[i][1][r];
                        s2 += acc[i][2][r];
                        s3 += acc[i][3][r];
                        any = true;
                    }
                }
            }
            if (any) {
                atomicAdd(&s_feat[li * 64 + 0 * 16 + ml], s0);
                atomicAdd(&s_feat[li * 64 + 1 * 16 + ml], s1);
                atomicAdd(&s_feat[li * 64 + 2 * 16 + ml], s2);
                atomicAdd(&s_feat[li * 64 + 3 * 16 + ml], s3);
            }
        }
        __syncthreads();
        for (int i = tid; i < nr * 64; i += 256) {
            float v = s_feat[i];
            if (v != 0.f)
                atomicAdd(&feat[((size_t)(n0 + n) * RR + s_rl[i >> 6]) * 64 + (i & 63)], v);
        }
    }
}

// ---------------------------------------------------------------------------
// Per-sample head: room MLP (64->128->128), room-sum, fc1 (128->256), fc2
// Loads FEAT (unnormalized masked sums) and multiplies by 1/room_size.
// ---------------------------------------------------------------------------
__global__ __launch_bounds__(256) void mlp_head(const float* __restrict__ feat,
                                                const float* __restrict__ HEAD,
                                                const float* __restrict__ rinv,
                                                const float* __restrict__ b1,
                                                const float* __restrict__ b2,
                                                const float* __restrict__ bf1,
                                                const float* __restrict__ bf2,
                                                float* __restrict__ outp)
{
    __shared__ __align__(16) float s_feat[RR * 64];
    __shared__ __align__(16) float s_h1[RR * 128];
    __shared__ __align__(16) float s_s[2 * 128];
    __shared__ __align__(16) float s_sf[128];
    __shared__ __align__(16) float s_t1[256];

    const int n = blockIdx.x;
    const int tid = threadIdx.x;
    const float* W1t = HEAD + F_WR1T;
    const float* W2t = HEAD + F_WR2T;
    const float* F1t = HEAD + F_F1T;
    const float* F2t = HEAD + F_F2T;

    for (int i = tid; i < RR * 64; i += 256)
        s_feat[i] = feat[(size_t)n * RR * 64 + i] * rinv[i >> 6];
    __syncthreads();

    const int o = tid & 127;
    const int rh = tid >> 7;

    float acc[16];
#pragma unroll
    for (int r = 0; r < 16; ++r) acc[r] = b1[o];
    for (int c4 = 0; c4 < 16; ++c4) {
        float w0 = W1t[(c4 * 4 + 0) * 128 + o];
        float w1 = W1t[(c4 * 4 + 1) * 128 + o];
        float w2 = W1t[(c4 * 4 + 2) * 128 + o];
        float w3 = W1t[(c4 * 4 + 3) * 128 + o];
#pragma unroll
        for (int r = 0; r < 16; ++r) {
            float4 f = *reinterpret_cast<const float4*>(&s_feat[(rh * 16 + r) * 64 + c4 * 4]);
            acc[r] += f.x * w0 + f.y * w1 + f.z * w2 + f.w * w3;
        }
    }
#pragma unroll
    for (int r = 0; r < 16; ++r) s_h1[(rh * 16 + r) * 128 + o] = fmaxf(acc[r], 0.f);
    __syncthreads();

#pragma unroll
    for (int r = 0; r < 16; ++r) acc[r] = b2[o];
    for (int c4 = 0; c4 < 32; ++c4) {
        float w0 = W2t[(c4 * 4 + 0) * 128 + o];
        float w1 = W2t[(c4 * 4 + 1) * 128 + o];
        float w2 = W2t[(c4 * 4 + 2) * 128 + o];
        float w3 = W2t[(c4 * 4 + 3) * 128 + o];
#pragma unroll
        for (int r = 0; r < 16; ++r) {
            float4 f = *reinterpret_cast<const float4*>(&s_h1[(rh * 16 + r) * 128 + c4 * 4]);
            acc[r] += f.x * w0 + f.y * w1 + f.z * w2 + f.w * w3;
        }
    }
    float ps = 0.f;
#pragma unroll
    for (int r = 0; r < 16; ++r) ps += fmaxf(acc[r], 0.f);
    s_s[rh * 128 + o] = ps;
    __syncthreads();
    if (tid < 128) s_sf[tid] = s_s[tid] + s_s[128 + tid];
    __syncthreads();

    {
        float a = bf1[tid];
        for (int c4 = 0; c4 < 32; ++c4) {
            float4 f = *reinterpret_cast<const float4*>(&s_sf[c4 * 4]);
            a += f.x * F1t[(c4 * 4 + 0) * 256 + tid];
            a += f.y * F1t[(c4 * 4 + 1) * 256 + tid];
            a += f.z * F1t[(c4 * 4 + 2) * 256 + tid];
            a += f.w * F1t[(c4 * 4 + 3) * 256 + tid];
        }
        s_t1[tid] = fmaxf(a, 0.f);
    }
    __syncthreads();

    {
        float a = bf2[tid];
        for (int c4 = 0; c4 < 64; ++c4) {
            float4 f = *reinterpret_cast<const float4*>(&s_t1[c4 * 4]);
            a += f.x * F2t[(c4 * 4 + 0) * 256 + tid];
            a += f.y * F2t[(c4 * 4 + 1) * 256 + tid];
            a += f.z * F2t[(c4 * 4 + 2) * 256 + tid];
            a += f.w * F2t[(c4 * 4 + 3) * 256 + tid];
        }
        outp[(size_t)n * 256 + tid] = a;
    }
}

// ---------------------------------------------------------------------------
extern "C" void kernel_launch(void* const* d_in, const int* in_sizes, int n_in,
                              void* d_out, int out_size, void* d_ws, size_t ws_size,
                              hipStream_t stream)
{
    const int* pos = (const int*)d_in[0];
    const float* rt = (const float*)d_in[1];
    const float* emb = (const float*)d_in[2];
    const float* w1 = (const float*)d_in[3];
    const float* bc1 = (const float*)d_in[4];
    const float* w2 = (const float*)d_in[5];
    const float* bc2 = (const float*)d_in[6];
    const float* w3 = (const float*)d_in[7];
    const float* bc3 = (const float*)d_in[8];
    const float* wr1 = (const float*)d_in[9];
    const float* br1 = (const float*)d_in[10];
    const float* wr2 = (const float*)d_in[11];
    const float* br2 = (const float*)d_in[12];
    const float* wf1 = (const float*)d_in[13];
    const float* bf1 = (const float*)d_in[14];
    const float* wf2 = (const float*)d_in[15];
    const float* bf2 = (const float*)d_in[16];
    float* out = (float*)d_out;
    char* ws = (char*)d_ws;

    prep_weights<<<880, 256, 0, stream>>>(w1, w2, w3, wr1, wr2, wf1, wf2, ws);
    prep_rooms<<<1, 64, 0, stream>>>(rt, ws);

    // pick largest batch chunk that fits the workspace
    int nc = 16;
    const int cands[4] = {256, 128, 64, 32};
    for (int k = 0; k < 4; ++k) {
        size_t need = B_CHUNK + (size_t)cands[k] * PERN_BYTES;
        if (need <= ws_size) { nc = cands[k]; break; }
    }

    short* W1F = (short*)(ws + B_W1F);
    short* W2F = (short*)(ws + B_W2F);
    short* W3F = (short*)(ws + B_W3F);
    const unsigned long long* RMASK = (const unsigned long long*)(ws + B_RAUX);
    const float* RINV = (const float*)(ws + B_RINV);
    float* HEAD = (float*)(ws + B_HEAD);
    float* FEAT = (float*)(ws + B_FEAT);
    short* Xc = (short*)(ws + B_CHUNK);
    short* YA = Xc + (size_t)nc * (MXY * MXY) * CIN1;
    short* YB = YA + (size_t)nc * (MXY * MXY) * 64;

    zero_feat<<<NB * RR * 64 / 256, 256, 0, stream>>>(FEAT);

    for (int n0 = 0; n0 < NB; n0 += nc) {
        build_x<<<dim3(21, nc), 256, 0, stream>>>(pos, rt, emb, Xc, n0);
        conv_mfma<16, 5, 14, 24, false><<<dim3(27, nc), 256, 0, stream>>>(
            Xc, W1F, bc1, YA, nullptr, nullptr, nullptr, 0);
        conv_mfma<64, 3, 18, 72, false><<<dim3(27, nc), 256, 0, stream>>>(
            YA, W2F, bc2, YB, nullptr, nullptr, nullptr, 0);
        conv_mfma<64, 3, 18, 72, true><<<dim3(27, nc), 256, 0, stream>>>(
            YB, W3F, bc3, nullptr, pos, RMASK, FEAT, n0);
    }

    mlp_head<<<NB, 256, 0, stream>>>(FEAT, HEAD, RINV, br1, br2, bf1, bf2, out);
}

// Round 3
// 325.267 us; speedup vs baseline: 2.1120x; 1.5480x over previous
//
#include <hip/hip_runtime.h>
#include <hip/hip_bf16.h>
#include <cstddef>

// Problem constants
#define NB 256   // batch
#define RR 32    // rooms
#define WW 8     // room width
#define HH 6     // room height
#define MXY 72   // map extent
#define EMB 6
#define CIN1 16  // 9 + 1 + 6

typedef __bf16 bf16x8 __attribute__((ext_vector_type(8)));
typedef float floatx4 __attribute__((ext_vector_type(4)));

// --- Workspace layout (byte offsets) ---------------------------------------
static const size_t B_W1F  = 0;         // 14 ksteps * 4096 B (only 13 used at run)
static const size_t B_W2F  = 57344;     // 18 * 4096
static const size_t B_W3F  = 131072;
static const size_t B_RAUX = 204800;    // room masks (32 u64)
static const size_t B_RINV = 205056;    // 1/room_size (32 f32)
static const size_t B_HEAD = 205312;    // fp32 head weights, 122880 floats
static const size_t F_WR1T = 0;         // (64,128)
static const size_t F_WR2T = 8192;      // (128,128)
static const size_t F_F1T  = 24576;     // (128,256)
static const size_t F_F2T  = 57344;     // (256,256)
static const size_t B_FEAT = 696832;    // (256,32,64) f32 = 2 MB
static const size_t B_CHUNK = 2793984;  // X buffer
static const size_t PERN_BYTES = 165888;  // X bf16 5184*16*2 (no Y buffers anymore!)

__device__ inline short f2b(float f) {
    unsigned u = __builtin_bit_cast(unsigned, f);
    unsigned r = (u + 0x7fffu + ((u >> 16) & 1u)) >> 16;
    return (short)r;
}

// ---------------------------------------------------------------------------
// Prep: conv weights fp32 -> bf16 B-fragment order; head weights transposed.
// Fragment order: [kk][ntile][lane][j] ; virtual k = kk*32 + (lane>>4)*8 + j
// oc = ntile*16 + (lane&15) ; (tap, ci) = (k / CIN, k % CIN)
// ---------------------------------------------------------------------------
__global__ void prep_weights(const float* __restrict__ w1, const float* __restrict__ w2,
                             const float* __restrict__ w3, const float* __restrict__ wr1,
                             const float* __restrict__ wr2, const float* __restrict__ wf1,
                             const float* __restrict__ wf2, char* __restrict__ ws)
{
    short* W1F = (short*)(ws + B_W1F);
    short* W2F = (short*)(ws + B_W2F);
    short* W3F = (short*)(ws + B_W3F);
    float* HEAD = (float*)(ws + B_HEAD);

    int idx = blockIdx.x * 256 + threadIdx.x;
    if (idx < 28672) {  // conv1: 14 ksteps (padded), CIN=16, taps 0..24 real
        int j = idx & 7, lane = (idx >> 3) & 63, nt = (idx >> 9) & 3, kk = idx >> 11;
        int k = kk * 32 + (lane >> 4) * 8 + j;
        int oc = nt * 16 + (lane & 15);
        int tap = k >> 4, ci = k & 15;
        float v = (tap < 25) ? w1[(oc * 16 + ci) * 25 + tap] : 0.f;
        W1F[idx] = f2b(v);
        return;
    }
    idx -= 28672;
    if (idx < 36864) {  // conv2: 18 ksteps, CIN=64, 9 taps
        int j = idx & 7, lane = (idx >> 3) & 63, nt = (idx >> 9) & 3, kk = idx >> 11;
        int k = kk * 32 + (lane >> 4) * 8 + j;
        int oc = nt * 16 + (lane & 15);
        int tap = k >> 6, ci = k & 63;
        W2F[idx] = f2b(w2[(oc * 64 + ci) * 9 + tap]);
        return;
    }
    idx -= 36864;
    if (idx < 36864) {  // conv3
        int j = idx & 7, lane = (idx >> 3) & 63, nt = (idx >> 9) & 3, kk = idx >> 11;
        int k = kk * 32 + (lane >> 4) * 8 + j;
        int oc = nt * 16 + (lane & 15);
        int tap = k >> 6, ci = k & 63;
        W3F[idx] = f2b(w3[(oc * 64 + ci) * 9 + tap]);
        return;
    }
    idx -= 36864;
    if (idx < 8192)  { int o = idx & 127, c = idx >> 7; HEAD[F_WR1T + idx] = wr1[o * 64 + c]; return; }
    idx -= 8192;
    if (idx < 16384) { int o = idx & 127, c = idx >> 7; HEAD[F_WR2T + idx] = wr2[o * 128 + c]; return; }
    idx -= 16384;
    if (idx < 32768) { int o = idx & 255, c = idx >> 8; HEAD[F_F1T + idx] = wf1[o * 128 + c]; return; }
    idx -= 32768;
    if (idx < 65536) { int o = idx & 255, c = idx >> 8; HEAD[F_F2T + idx] = wf2[o * 256 + c]; return; }
}

// Room footprint bitmasks (48 bits) + 1/room_size.
__global__ void prep_rooms(const float* __restrict__ rt, char* __restrict__ ws)
{
    int r = threadIdx.x;
    if (r >= RR) return;
    unsigned long long m = 0ull;
    int cnt = 0;
    for (int j = 0; j < WW * HH; ++j)
        if (rt[r * 9 * 48 + j] != 0.f) { m |= (1ull << j); ++cnt; }
    ((unsigned long long*)(ws + B_RAUX))[r] = m;
    ((float*)(ws + B_RINV))[r] = 1.f / (float)cnt;
}

// ---------------------------------------------------------------------------
// Build X (nc, 72, 72, 16) NHWC bf16 — GATHER style.
// ---------------------------------------------------------------------------
__global__ __launch_bounds__(256) void build_x(const int* __restrict__ pos,
                                               const float* __restrict__ rt,
                                               const float* __restrict__ emb,
                                               short* __restrict__ X, int n0)
{
    const int nl = blockIdx.y;
    const int n = n0 + nl;
    const int p = blockIdx.x * 256 + threadIdx.x;

    __shared__ int s_px[RR], s_py[RR];
    __shared__ float s_emb[RR * EMB];
    if (threadIdx.x < RR) {
        s_px[threadIdx.x] = pos[(n * RR + threadIdx.x) * 2 + 0];
        s_py[threadIdx.x] = pos[(n * RR + threadIdx.x) * 2 + 1];
    }
    for (int i = threadIdx.x; i < RR * EMB; i += 256) s_emb[i] = emb[i];
    __syncthreads();
    if (p >= MXY * MXY) return;

    const int gx = p / MXY, gy = p - (p / MXY) * MXY;

    float acc[16];
#pragma unroll
    for (int c = 0; c < 16; ++c) acc[c] = 0.f;
    acc[9] = 1.f;

    for (int r = 0; r < RR; ++r) {
        int w = gx - s_px[r], h = gy - s_py[r];
        if ((unsigned)w < (unsigned)WW && (unsigned)h < (unsigned)HH) {
            int j = w * HH + h;
            const float* rr = rt + r * 9 * 48;
#pragma unroll
            for (int c = 0; c < 9; ++c) acc[c] += rr[c * 48 + j];
            float m = rr[j];  // channel 0 = room_map
#pragma unroll
            for (int e = 0; e < EMB; ++e) acc[10 + e] += s_emb[r * EMB + e] * m;
        }
    }

    short o[16];
#pragma unroll
    for (int c = 0; c < 16; ++c) o[c] = f2b(acc[c]);
    short* dst = X + ((size_t)nl * (MXY * MXY) + p) * CIN1;
    *reinterpret_cast<uint4*>(dst) = *reinterpret_cast<uint4*>(o);
    *reinterpret_cast<uint4*>(dst + 8) = *reinterpret_cast<uint4*>(o + 8);
}

// ---------------------------------------------------------------------------
// ROUND-3 FUSED PER-ROOM CONV CHAIN. Block = (sample, room), 4 waves.
//
// Rationale (rounds 0-2 evidence): full-map conv is latency-bound with every
// pipe at 25-30%; writes/LDS-size/occupancy knobs all failed. But conv
// outputs are only CONSUMED on room footprints (30% of map): per-room tiles
// halve the MFMA count AND let Y1/Y2 live entirely in LDS (zero inter-conv
// global traffic; was ~108MB fetch + 166MB write per chunk-pass).
//
//   stage X 16x14x16ch (CIP=24, 2-way-free banks) into s_u       [7  KB]
//   conv1 5x5: out 12x10x64 -> s_Y1 (CIP=72)                     [17 KB]
//   conv2 3x3: out 10x8x64  -> s_u  (aliases dead X)             [11.5 KB]
//   conv3 3x3: out 8x6x64, masked room-sum via shfl_xor -> FEAT row
//
// Wave split: M-split (waves own pixels, share all 4 oc-tiles) — N-split is
// LDS-bound (prev session). B frags ping-pong in regs, prefetch chained
// ACROSS stages (round-1 lesson: removing ping-pong exposes L2 latency).
// m-tiles/wave: conv1 {2wv,2wv+1}; conv2 {wv}+{4 for wv0}; conv3 {wv<3}.
// LDS 29KB -> 5 blocks/CU; regs ~96 -> __launch_bounds__(256,5), 20 waves/CU.
// FEAT rows are block-exclusive: no atomics, no zero pass.
// Pure-MFMA floor: 8192 blk x 1024 MFMA x 4.85cyc / 256CU = 66us total.
// ---------------------------------------------------------------------------
__global__ __launch_bounds__(256, 5) void fused_conv(const short* __restrict__ X,
    const short* __restrict__ W1F, const short* __restrict__ W2F,
    const short* __restrict__ W3F, const float* __restrict__ bc1,
    const float* __restrict__ bc2, const float* __restrict__ bc3,
    const int* __restrict__ pos, const unsigned long long* __restrict__ rmask,
    float* __restrict__ feat, int n0)
{
    __shared__ __align__(16) short s_Y1[120 * 72];  // 17280 B
    __shared__ __align__(16) short s_u[80 * 72];    // 11520 B: X[224][24] then Y2[80][72]
    __shared__ float s_feat[64];

    const int tid = threadIdx.x;
    const int lane = tid & 63;
    const int wv = tid >> 6;
    const int ml = lane & 15;
    const int q = lane >> 4;
    const int room = blockIdx.x;
    const int nl = blockIdx.y;
    const int n = n0 + nl;

    const int px = pos[(n * RR + room) * 2 + 0];
    const int py = pos[(n * RR + room) * 2 + 1];

    bf16x8 Bb[2][4];
    auto load_k = [&](const short* wF, int kk, bf16x8* dst) {
        const short* src = wF + (size_t)kk * 2048;
#pragma unroll
        for (int j2 = 0; j2 < 4; ++j2)
            dst[j2] = *reinterpret_cast<const bf16x8*>(src + (j2 * 64 + lane) * 8);
    };
    load_k(W1F, 0, Bb[0]);

    // ---- stage X tile: rows px-4..px+11, cols py-4..py+9, zero-padded ----
    const short* Xn = X + (size_t)nl * (MXY * MXY) * CIN1;
    for (int i = tid; i < 448; i += 256) {
        int half = i & 1, pix = i >> 1;
        int row = pix / 14, col = pix - row * 14;
        int gx = px - 4 + row, gy = py - 4 + col;
        uint4 v = make_uint4(0u, 0u, 0u, 0u);
        if ((unsigned)gx < (unsigned)MXY && (unsigned)gy < (unsigned)MXY)
            v = *reinterpret_cast<const uint4*>(Xn + ((size_t)gx * MXY + gy) * CIN1 + half * 8);
        *reinterpret_cast<uint4*>(&s_u[pix * 24 + half * 8]) = v;
    }
    __syncthreads();

    floatx4 acc[2][4];

    // ---- conv1: 5x5, X(16ch) -> Y1 on 12x10 (8 m-tiles, 2/wave) ----
    {
        int prow[2], pcol[2];
#pragma unroll
        for (int i = 0; i < 2; ++i) {
            int p = wv * 32 + i * 16 + ml;
            if (p > 119) p = 119;  // pad px: duplicate compute, discarded
            prow[i] = p / 10; pcol[i] = p - prow[i] * 10;
        }
#pragma unroll
        for (int i = 0; i < 2; ++i)
#pragma unroll
            for (int j2 = 0; j2 < 4; ++j2) acc[i][j2] = (floatx4){0.f, 0.f, 0.f, 0.f};

#pragma unroll
        for (int kk = 0; kk < 13; ++kk) {  // taps 0..25 (25 is zero-pad)
            if (kk < 12) load_k(W1F, kk + 1, Bb[(kk + 1) & 1]);
            else         load_k(W2F, 0, Bb[1]);  // chain prefetch into conv2
            int tap = kk * 2 + (q >> 1);
            if (tap > 24) tap = 24;
            int chb = (q & 1) * 8;
            int dx = tap / 5, dy = tap - dx * 5;
#pragma unroll
            for (int i = 0; i < 2; ++i) {
                bf16x8 A = *reinterpret_cast<const bf16x8*>(
                    &s_u[((prow[i] + dx) * 14 + (pcol[i] + dy)) * 24 + chb]);
#pragma unroll
                for (int j2 = 0; j2 < 4; ++j2)
                    acc[i][j2] = __builtin_amdgcn_mfma_f32_16x16x32_bf16(
                        A, Bb[kk & 1][j2], acc[i][j2], 0, 0, 0);
            }
        }
        float b4[4];
#pragma unroll
        for (int j2 = 0; j2 < 4; ++j2) b4[j2] = bc1[j2 * 16 + ml];
#pragma unroll
        for (int i = 0; i < 2; ++i)
#pragma unroll
            for (int r = 0; r < 4; ++r) {
                int p = wv * 32 + i * 16 + q * 4 + r;
                if (p < 120) {
#pragma unroll
                    for (int j2 = 0; j2 < 4; ++j2)
                        s_Y1[p * 72 + j2 * 16 + ml] = f2b(fmaxf(acc[i][j2][r] + b4[j2], 0.f));
                }
            }
    }
    __syncthreads();  // Y1 complete; X (s_u) dead

    // ---- conv2: 3x3, Y1 -> Y2 on 10x8 (5 m-tiles: wv + {4 on wv0}) ----
    {
        int prow[2], pcol[2];
        {
            int p0 = wv * 16 + ml;
            prow[0] = p0 >> 3; pcol[0] = p0 & 7;
            int p1 = 64 + ml;
            prow[1] = p1 >> 3; pcol[1] = p1 & 7;
        }
#pragma unroll
        for (int i = 0; i < 2; ++i)
#pragma unroll
            for (int j2 = 0; j2 < 4; ++j2) acc[i][j2] = (floatx4){0.f, 0.f, 0.f, 0.f};

#pragma unroll
        for (int kk = 0; kk < 18; ++kk) {
            if (kk < 17) load_k(W2F, kk + 1, Bb[kk & 1]);
            else         load_k(W3F, 0, Bb[1]);  // chain prefetch into conv3
            int tap = kk >> 1;
            int chb = (kk & 1) * 32 + q * 8;
            int dx = tap / 3, dy = tap - dx * 3;
            bf16x8 A = *reinterpret_cast<const bf16x8*>(
                &s_Y1[((prow[0] + dx) * 10 + (pcol[0] + dy)) * 72 + chb]);
#pragma unroll
            for (int j2 = 0; j2 < 4; ++j2)
                acc[0][j2] = __builtin_amdgcn_mfma_f32_16x16x32_bf16(
                    A, Bb[(kk + 1) & 1][j2], acc[0][j2], 0, 0, 0);
            if (wv == 0) {  // wave-uniform branch: 5th m-tile
                bf16x8 A1 = *reinterpret_cast<const bf16x8*>(
                    &s_Y1[((prow[1] + dx) * 10 + (pcol[1] + dy)) * 72 + chb]);
#pragma unroll
                for (int j2 = 0; j2 < 4; ++j2)
                    acc[1][j2] = __builtin_amdgcn_mfma_f32_16x16x32_bf16(
                        A1, Bb[(kk + 1) & 1][j2], acc[1][j2], 0, 0, 0);
            }
        }
        float b4[4];
#pragma unroll
        for (int j2 = 0; j2 < 4; ++j2) b4[j2] = bc2[j2 * 16 + ml];
#pragma unroll
        for (int r = 0; r < 4; ++r) {
            int p = wv * 16 + q * 4 + r;
#pragma unroll
            for (int j2 = 0; j2 < 4; ++j2)
                s_u[p * 72 + j2 * 16 + ml] = f2b(fmaxf(acc[0][j2][r] + b4[j2], 0.f));
        }
        if (wv == 0) {
#pragma unroll
            for (int r = 0; r < 4; ++r) {
                int p = 64 + q * 4 + r;
#pragma unroll
                for (int j2 = 0; j2 < 4; ++j2)
                    s_u[p * 72 + j2 * 16 + ml] = f2b(fmaxf(acc[1][j2][r] + b4[j2], 0.f));
            }
        }
        if (tid < 64) s_feat[tid] = 0.f;
    }
    __syncthreads();  // Y2 complete

    // ---- conv3: 3x3, Y2 -> 8x6 masked room-sum (3 m-tiles, waves 0-2) ----
    if (wv < 3) {
        int p0 = wv * 16 + ml;
        int row = p0 / 6, col = p0 - row * 6;
#pragma unroll
        for (int j2 = 0; j2 < 4; ++j2) acc[0][j2] = (floatx4){0.f, 0.f, 0.f, 0.f};

#pragma unroll
        for (int kk = 0; kk < 18; ++kk) {
            if (kk < 17) load_k(W3F, kk + 1, Bb[kk & 1]);
            int tap = kk >> 1;
            int chb = (kk & 1) * 32 + q * 8;
            int dx = tap / 3, dy = tap - dx * 3;
            bf16x8 A = *reinterpret_cast<const bf16x8*>(
                &s_u[((row + dx) * 8 + (col + dy)) * 72 + chb]);
#pragma unroll
            for (int j2 = 0; j2 < 4; ++j2)
                acc[0][j2] = __builtin_amdgcn_mfma_f32_16x16x32_bf16(
                    A, Bb[(kk + 1) & 1][j2], acc[0][j2], 0, 0, 0);
        }
        float b4[4];
#pragma unroll
        for (int j2 = 0; j2 < 4; ++j2) b4[j2] = bc3[j2 * 16 + ml];
        float part[4] = {0.f, 0.f, 0.f, 0.f};
        const unsigned long long mk = rmask[room];
#pragma unroll
        for (int r = 0; r < 4; ++r) {
            int p = wv * 16 + q * 4 + r;  // == w*6+h == mask bit index
            if ((mk >> p) & 1ull) {
#pragma unroll
                for (int j2 = 0; j2 < 4; ++j2)
                    part[j2] += fmaxf(acc[0][j2][r] + b4[j2], 0.f);
            }
        }
#pragma unroll
        for (int j2 = 0; j2 < 4; ++j2) {
            part[j2] += __shfl_xor(part[j2], 16);
            part[j2] += __shfl_xor(part[j2], 32);
        }
        if (q == 0) {
#pragma unroll
            for (int j2 = 0; j2 < 4; ++j2)
                atomicAdd(&s_feat[j2 * 16 + ml], part[j2]);  // 3 contenders
        }
    }
    __syncthreads();
    if (tid < 64)
        feat[((size_t)n * RR + room) * 64 + tid] = s_feat[tid];
}

// ---------------------------------------------------------------------------
// Per-sample head: room MLP (64->128->128), room-sum, fc1, fc2.
// FEAT holds unnormalized masked sums; normalize by rinv here.
// ---------------------------------------------------------------------------
__global__ __launch_bounds__(256) void mlp_head(const float* __restrict__ feat,
                                                const float* __restrict__ HEAD,
                                                const float* __restrict__ rinv,
                                                const float* __restrict__ b1,
                                                const float* __restrict__ b2,
                                                const float* __restrict__ bf1,
                                                const float* __restrict__ bf2,
                                                float* __restrict__ outp)
{
    __shared__ __align__(16) float s_feat[RR * 64];
    __shared__ __align__(16) float s_h1[RR * 128];
    __shared__ __align__(16) float s_s[2 * 128];
    __shared__ __align__(16) float s_sf[128];
    __shared__ __align__(16) float s_t1[256];

    const int n = blockIdx.x;
    const int tid = threadIdx.x;
    const float* W1t = HEAD + F_WR1T;
    const float* W2t = HEAD + F_WR2T;
    const float* F1t = HEAD + F_F1T;
    const float* F2t = HEAD + F_F2T;

    for (int i = tid; i < RR * 64; i += 256)
        s_feat[i] = feat[(size_t)n * RR * 64 + i] * rinv[i >> 6];
    __syncthreads();

    const int o = tid & 127;
    const int rh = tid >> 7;

    float acc[16];
#pragma unroll
    for (int r = 0; r < 16; ++r) acc[r] = b1[o];
    for (int c4 = 0; c4 < 16; ++c4) {
        float w0 = W1t[(c4 * 4 + 0) * 128 + o];
        float w1 = W1t[(c4 * 4 + 1) * 128 + o];
        float w2 = W1t[(c4 * 4 + 2) * 128 + o];
        float w3 = W1t[(c4 * 4 + 3) * 128 + o];
#pragma unroll
        for (int r = 0; r < 16; ++r) {
            float4 f = *reinterpret_cast<const float4*>(&s_feat[(rh * 16 + r) * 64 + c4 * 4]);
            acc[r] += f.x * w0 + f.y * w1 + f.z * w2 + f.w * w3;
        }
    }
#pragma unroll
    for (int r = 0; r < 16; ++r) s_h1[(rh * 16 + r) * 128 + o] = fmaxf(acc[r], 0.f);
    __syncthreads();

#pragma unroll
    for (int r = 0; r < 16; ++r) acc[r] = b2[o];
    for (int c4 = 0; c4 < 32; ++c4) {
        float w0 = W2t[(c4 * 4 + 0) * 128 + o];
        float w1 = W2t[(c4 * 4 + 1) * 128 + o];
        float w2 = W2t[(c4 * 4 + 2) * 128 + o];
        float w3 = W2t[(c4 * 4 + 3) * 128 + o];
#pragma unroll
        for (int r = 0; r < 16; ++r) {
            float4 f = *reinterpret_cast<const float4*>(&s_h1[(rh * 16 + r) * 128 + c4 * 4]);
            acc[r] += f.x * w0 + f.y * w1 + f.z * w2 + f.w * w3;
        }
    }
    float ps = 0.f;
#pragma unroll
    for (int r = 0; r < 16; ++r) ps += fmaxf(acc[r], 0.f);
    s_s[rh * 128 + o] = ps;
    __syncthreads();
    if (tid < 128) s_sf[tid] = s_s[tid] + s_s[128 + tid];
    __syncthreads();

    {
        float a = bf1[tid];
        for (int c4 = 0; c4 < 32; ++c4) {
            float4 f = *reinterpret_cast<const float4*>(&s_sf[c4 * 4]);
            a += f.x * F1t[(c4 * 4 + 0) * 256 + tid];
            a += f.y * F1t[(c4 * 4 + 1) * 256 + tid];
            a += f.z * F1t[(c4 * 4 + 2) * 256 + tid];
            a += f.w * F1t[(c4 * 4 + 3) * 256 + tid];
        }
        s_t1[tid] = fmaxf(a, 0.f);
    }
    __syncthreads();

    {
        float a = bf2[tid];
        for (int c4 = 0; c4 < 64; ++c4) {
            float4 f = *reinterpret_cast<const float4*>(&s_t1[c4 * 4]);
            a += f.x * F2t[(c4 * 4 + 0) * 256 + tid];
            a += f.y * F2t[(c4 * 4 + 1) * 256 + tid];
            a += f.z * F2t[(c4 * 4 + 2) * 256 + tid];
            a += f.w * F2t[(c4 * 4 + 3) * 256 + tid];
        }
        outp[(size_t)n * 256 + tid] = a;
    }
}

// ---------------------------------------------------------------------------
extern "C" void kernel_launch(void* const* d_in, const int* in_sizes, int n_in,
                              void* d_out, int out_size, void* d_ws, size_t ws_size,
                              hipStream_t stream)
{
    const int* pos = (const int*)d_in[0];
    const float* rt = (const float*)d_in[1];
    const float* emb = (const float*)d_in[2];
    const float* w1 = (const float*)d_in[3];
    const float* bc1 = (const float*)d_in[4];
    const float* w2 = (const float*)d_in[5];
    const float* bc2 = (const float*)d_in[6];
    const float* w3 = (const float*)d_in[7];
    const float* bc3 = (const float*)d_in[8];
    const float* wr1 = (const float*)d_in[9];
    const float* br1 = (const float*)d_in[10];
    const float* wr2 = (const float*)d_in[11];
    const float* br2 = (const float*)d_in[12];
    const float* wf1 = (const float*)d_in[13];
    const float* bf1 = (const float*)d_in[14];
    const float* wf2 = (const float*)d_in[15];
    const float* bf2 = (const float*)d_in[16];
    float* out = (float*)d_out;
    char* ws = (char*)d_ws;

    prep_weights<<<880, 256, 0, stream>>>(w1, w2, w3, wr1, wr2, wf1, wf2, ws);
    prep_rooms<<<1, 64, 0, stream>>>(rt, ws);

    // largest batch chunk whose X buffer fits the workspace
    int nc = 16;
    const int cands[4] = {256, 128, 64, 32};
    for (int k = 0; k < 4; ++k) {
        size_t need = B_CHUNK + (size_t)cands[k] * PERN_BYTES;
        if (need <= ws_size) { nc = cands[k]; break; }
    }

    short* W1F = (short*)(ws + B_W1F);
    short* W2F = (short*)(ws + B_W2F);
    short* W3F = (short*)(ws + B_W3F);
    const unsigned long long* RMASK = (const unsigned long long*)(ws + B_RAUX);
    const float* RINV = (const float*)(ws + B_RINV);
    float* HEAD = (float*)(ws + B_HEAD);
    float* FEAT = (float*)(ws + B_FEAT);
    short* Xc = (short*)(ws + B_CHUNK);

    for (int n0 = 0; n0 < NB; n0 += nc) {
        build_x<<<dim3(21, nc), 256, 0, stream>>>(pos, rt, emb, Xc, n0);
        fused_conv<<<dim3(RR, nc), 256, 0, stream>>>(Xc, W1F, W2F, W3F,
                                                     bc1, bc2, bc3, pos, RMASK, FEAT, n0);
    }

    mlp_head<<<NB, 256, 0, stream>>>(FEAT, HEAD, RINV, br1, br2, bf1, bf2, out);
}

// Round 4
// 313.305 us; speedup vs baseline: 2.1927x; 1.0382x over previous
//
#include <hip/hip_runtime.h>
#include <hip/hip_bf16.h>
#include <cstddef>

// Problem constants
#define NB 256   // batch
#define RR 32    // rooms
#define WW 8     // room width
#define HH 6     // room height
#define MXY 72   // map extent
#define EMB 6
#define CIN1 16  // 9 + 1 + 6

typedef __bf16 bf16x8 __attribute__((ext_vector_type(8)));
typedef float floatx4 __attribute__((ext_vector_type(4)));

// --- Workspace layout (byte offsets) ---------------------------------------
// Conv weights are packed as 25 contiguous 8KB "phases":
//   W1F: 7 phases (14 ksteps)  [0,57344)
//   W2F: 9 phases (18 ksteps)  [57344,131072)
//   W3F: 9 phases (18 ksteps)  [131072,204800)
// fused_conv DMA-streams these linearly phase-by-phase into LDS.
static const size_t B_W1F  = 0;
static const size_t B_W2F  = 57344;
static const size_t B_W3F  = 131072;
static const size_t B_RAUX = 204800;    // room masks (32 u64)
static const size_t B_RINV = 205056;    // 1/room_size (32 f32)
static const size_t B_HEAD = 205312;    // fp32 head weights, 122880 floats
static const size_t F_WR1T = 0;         // (64,128)
static const size_t F_WR2T = 8192;      // (128,128)
static const size_t F_F1T  = 24576;     // (128,256)
static const size_t F_F2T  = 57344;     // (256,256)
static const size_t B_FEAT = 696832;    // (256,32,64) f32 = 2 MB
static const size_t B_CHUNK = 2793984;  // X buffer
static const size_t PERN_BYTES = 165888;  // X bf16 5184*16*2

__device__ inline short f2b(float f) {
    unsigned u = __builtin_bit_cast(unsigned, f);
    unsigned r = (u + 0x7fffu + ((u >> 16) & 1u)) >> 16;
    return (short)r;
}

// ---------------------------------------------------------------------------
// Prep: conv weights fp32 -> bf16 B-fragment order; head weights transposed.
// Fragment order: [kk][ntile][lane][j] ; virtual k = kk*32 + (lane>>4)*8 + j
// oc = ntile*16 + (lane&15).
// conv1: (tap,ci) natural (X is stored in natural channel order).
// conv2/3: input position c' maps to channel ci = (c'>>2) + (c'&3)*16 — the
// paired-channel layout Y1/Y2 are written in (lane packs its 4 j2 outputs
// contiguously -> b64 LDS stores instead of 16 scalar b16 stores).
// ---------------------------------------------------------------------------
__global__ void prep_weights(const float* __restrict__ w1, const float* __restrict__ w2,
                             const float* __restrict__ w3, const float* __restrict__ wr1,
                             const float* __restrict__ wr2, const float* __restrict__ wf1,
                             const float* __restrict__ wf2, char* __restrict__ ws)
{
    short* W1F = (short*)(ws + B_W1F);
    short* W2F = (short*)(ws + B_W2F);
    short* W3F = (short*)(ws + B_W3F);
    float* HEAD = (float*)(ws + B_HEAD);

    int idx = blockIdx.x * 256 + threadIdx.x;
    if (idx < 28672) {  // conv1: 14 ksteps (padded), CIN=16, taps 0..24 real
        int j = idx & 7, lane = (idx >> 3) & 63, nt = (idx >> 9) & 3, kk = idx >> 11;
        int k = kk * 32 + (lane >> 4) * 8 + j;
        int oc = nt * 16 + (lane & 15);
        int tap = k >> 4, ci = k & 15;
        float v = (tap < 25) ? w1[(oc * 16 + ci) * 25 + tap] : 0.f;
        W1F[idx] = f2b(v);
        return;
    }
    idx -= 28672;
    if (idx < 36864) {  // conv2: 18 ksteps, CIN=64, 9 taps, permuted ci
        int j = idx & 7, lane = (idx >> 3) & 63, nt = (idx >> 9) & 3, kk = idx >> 11;
        int k = kk * 32 + (lane >> 4) * 8 + j;
        int oc = nt * 16 + (lane & 15);
        int tap = k >> 6, cp = k & 63;
        int ci = (cp >> 2) + (cp & 3) * 16;
        W2F[idx] = f2b(w2[(oc * 64 + ci) * 9 + tap]);
        return;
    }
    idx -= 36864;
    if (idx < 36864) {  // conv3, permuted ci
        int j = idx & 7, lane = (idx >> 3) & 63, nt = (idx >> 9) & 3, kk = idx >> 11;
        int k = kk * 32 + (lane >> 4) * 8 + j;
        int oc = nt * 16 + (lane & 15);
        int tap = k >> 6, cp = k & 63;
        int ci = (cp >> 2) + (cp & 3) * 16;
        W3F[idx] = f2b(w3[(oc * 64 + ci) * 9 + tap]);
        return;
    }
    idx -= 36864;
    if (idx < 8192)  { int o = idx & 127, c = idx >> 7; HEAD[F_WR1T + idx] = wr1[o * 64 + c]; return; }
    idx -= 8192;
    if (idx < 16384) { int o = idx & 127, c = idx >> 7; HEAD[F_WR2T + idx] = wr2[o * 128 + c]; return; }
    idx -= 16384;
    if (idx < 32768) { int o = idx & 255, c = idx >> 8; HEAD[F_F1T + idx] = wf1[o * 128 + c]; return; }
    idx -= 32768;
    if (idx < 65536) { int o = idx & 255, c = idx >> 8; HEAD[F_F2T + idx] = wf2[o * 256 + c]; return; }
}

// Room footprint bitmasks (48 bits) + 1/room_size.
__global__ void prep_rooms(const float* __restrict__ rt, char* __restrict__ ws)
{
    int r = threadIdx.x;
    if (r >= RR) return;
    unsigned long long m = 0ull;
    int cnt = 0;
    for (int j = 0; j < WW * HH; ++j)
        if (rt[r * 9 * 48 + j] != 0.f) { m |= (1ull << j); ++cnt; }
    ((unsigned long long*)(ws + B_RAUX))[r] = m;
    ((float*)(ws + B_RINV))[r] = 1.f / (float)cnt;
}

// ---------------------------------------------------------------------------
// Build X (nc, 72, 72, 16) NHWC bf16 — GATHER style.
// ---------------------------------------------------------------------------
__global__ __launch_bounds__(256) void build_x(const int* __restrict__ pos,
                                               const float* __restrict__ rt,
                                               const float* __restrict__ emb,
                                               short* __restrict__ X, int n0)
{
    const int nl = blockIdx.y;
    const int n = n0 + nl;
    const int p = blockIdx.x * 256 + threadIdx.x;

    __shared__ int s_px[RR], s_py[RR];
    __shared__ float s_emb[RR * EMB];
    if (threadIdx.x < RR) {
        s_px[threadIdx.x] = pos[(n * RR + threadIdx.x) * 2 + 0];
        s_py[threadIdx.x] = pos[(n * RR + threadIdx.x) * 2 + 1];
    }
    for (int i = threadIdx.x; i < RR * EMB; i += 256) s_emb[i] = emb[i];
    __syncthreads();
    if (p >= MXY * MXY) return;

    const int gx = p / MXY, gy = p - (p / MXY) * MXY;

    float acc[16];
#pragma unroll
    for (int c = 0; c < 16; ++c) acc[c] = 0.f;
    acc[9] = 1.f;

    for (int r = 0; r < RR; ++r) {
        int w = gx - s_px[r], h = gy - s_py[r];
        if ((unsigned)w < (unsigned)WW && (unsigned)h < (unsigned)HH) {
            int j = w * HH + h;
            const float* rr = rt + r * 9 * 48;
#pragma unroll
            for (int c = 0; c < 9; ++c) acc[c] += rr[c * 48 + j];
            float m = rr[j];  // channel 0 = room_map
#pragma unroll
            for (int e = 0; e < EMB; ++e) acc[10 + e] += s_emb[r * EMB + e] * m;
        }
    }

    short o[16];
#pragma unroll
    for (int c = 0; c < 16; ++c) o[c] = f2b(acc[c]);
    short* dst = X + ((size_t)nl * (MXY * MXY) + p) * CIN1;
    *reinterpret_cast<uint4*>(dst) = *reinterpret_cast<uint4*>(o);
    *reinterpret_cast<uint4*>(dst + 8) = *reinterpret_cast<uint4*>(o + 8);
}

// ---------------------------------------------------------------------------
// ROUND-4 FUSED PER-ROOM CONV CHAIN with LDS-staged weights.
//
// Round-3 diagnosis: per-wave B loads from global = 6.4 GB of L2 traffic
// (4 waves x identical 4KB/kstep x 49 ksteps x 8192 blocks) = 30 TB/s
// ~= the L2 ceiling -> the kernel was L2-BW-bound on weight re-fetch.
//
// Fix: one DMA stream per block. All conv weights are 25 contiguous 8KB
// phases in ws; phase p computes 2 ksteps from s_B[p&1] while DMAing phase
// p+1 into s_B[(p+1)&1] via global_load_lds. __syncthreads per phase is the
// double-buffer handshake (its implicit vmcnt-drain covers the DMA).
// L2 B-traffic: 6.4 GB -> 1.6 GB.
//
// Also: paired-channel Y1/Y2 layout (channel c at position (c&15)*4+(c>>4);
// conv2/3 weights pre-permuted to match) -> epilogue writes are b64 instead
// of 16 scalar b16 -> kills the 15.4M bank-conflict cycles.
// conv2's 5th m-tile is n-split across waves (balanced 5 MFMA/kstep).
//
// LDS: Y1 17280 + s_u 11520 + s_B 16384 + feat 256 = 45.4 KB -> 3 blocks/CU.
// ---------------------------------------------------------------------------
__global__ __launch_bounds__(256, 3) void fused_conv(const short* __restrict__ X,
    const short* __restrict__ wAll, const float* __restrict__ bc1,
    const float* __restrict__ bc2, const float* __restrict__ bc3,
    const int* __restrict__ pos, const unsigned long long* __restrict__ rmask,
    float* __restrict__ feat, int n0)
{
    __shared__ __align__(16) short s_Y1[120 * 72];   // 17280 B, paired-channel
    __shared__ __align__(16) short s_u[80 * 72];     // X[224][24] then Y2[80][72]
    __shared__ __align__(16) short s_B[2][4096];     // weight phase double-buffer
    __shared__ float s_feat[64];

    const int tid = threadIdx.x;
    const int lane = tid & 63;
    const int wv = tid >> 6;
    const int ml = lane & 15;
    const int q = lane >> 4;
    const int room = blockIdx.x;
    const int nl = blockIdx.y;
    const int n = n0 + nl;

    const int px = pos[(n * RR + room) * 2 + 0];
    const int py = pos[(n * RR + room) * 2 + 1];

    const char* wB = (const char*)wAll;
    // DMA one 8KB weight phase into its parity buffer (2KB per wave, 2x1KB)
    auto dma = [&](int ph) {
        const char* src = wB + (size_t)ph * 8192 + wv * 2048 + lane * 16;
        short* d0 = &s_B[ph & 1][wv * 1024];
        __builtin_amdgcn_global_load_lds(
            (const __attribute__((address_space(1))) unsigned int*)src,
            (__attribute__((address_space(3))) unsigned int*)d0, 16, 0, 0);
        __builtin_amdgcn_global_load_lds(
            (const __attribute__((address_space(1))) unsigned int*)(src + 1024),
            (__attribute__((address_space(3))) unsigned int*)(d0 + 512), 16, 0, 0);
    };

    dma(0);

    // ---- stage X tile: rows px-4..px+11, cols py-4..py+9, zero-padded ----
    const short* Xn = X + (size_t)nl * (MXY * MXY) * CIN1;
    for (int i = tid; i < 448; i += 256) {
        int half = i & 1, pix = i >> 1;
        int row = pix / 14, col = pix - row * 14;
        int gx = px - 4 + row, gy = py - 4 + col;
        uint4 v = make_uint4(0u, 0u, 0u, 0u);
        if ((unsigned)gx < (unsigned)MXY && (unsigned)gy < (unsigned)MXY)
            v = *reinterpret_cast<const uint4*>(Xn + ((size_t)gx * MXY + gy) * CIN1 + half * 8);
        *reinterpret_cast<uint4*>(&s_u[pix * 24 + half * 8]) = v;
    }
    __syncthreads();  // X staged, weight phase 0 resident

    // ================= conv1: 5x5, X(16ch) -> Y1 12x10x64 =================
    {
        int prow[2], pcol[2];
#pragma unroll
        for (int i = 0; i < 2; ++i) {
            int p = wv * 32 + i * 16 + ml;
            if (p > 119) p = 119;  // pad px: duplicate compute, discarded
            prow[i] = p / 10; pcol[i] = p - prow[i] * 10;
        }
        floatx4 acc1[2][4] = {};

#pragma unroll
        for (int t = 0; t < 7; ++t) {
            dma(t + 1);  // phases 1..7 (7 = conv2 ksteps 0-1)
            const short* sb = s_B[t & 1];
#pragma unroll
            for (int kb = 0; kb < 2; ++kb) {
                const int kk = t * 2 + kb;
                bf16x8 Bf[4];
#pragma unroll
                for (int j2 = 0; j2 < 4; ++j2)
                    Bf[j2] = *reinterpret_cast<const bf16x8*>(&sb[kb * 2048 + (j2 * 64 + lane) * 8]);
                int tap = kk * 2 + (q >> 1);
                if (tap > 24) tap = 24;  // padded-tail weights are zero
                const int chb = (q & 1) * 8;
                const int dx = tap / 5, dy = tap - (tap / 5) * 5;
                __builtin_amdgcn_s_setprio(1);
#pragma unroll
                for (int i = 0; i < 2; ++i) {
                    bf16x8 A = *reinterpret_cast<const bf16x8*>(
                        &s_u[((prow[i] + dx) * 14 + (pcol[i] + dy)) * 24 + chb]);
#pragma unroll
                    for (int j2 = 0; j2 < 4; ++j2)
                        acc1[i][j2] = __builtin_amdgcn_mfma_f32_16x16x32_bf16(
                            A, Bf[j2], acc1[i][j2], 0, 0, 0);
                }
                __builtin_amdgcn_s_setprio(0);
            }
            if (t == 6) {  // epilogue: bias+relu, b64 paired-channel stores
                float b4[4];
#pragma unroll
                for (int j2 = 0; j2 < 4; ++j2) b4[j2] = bc1[j2 * 16 + ml];
#pragma unroll
                for (int i = 0; i < 2; ++i)
#pragma unroll
                    for (int r = 0; r < 4; ++r) {
                        int p = wv * 32 + i * 16 + q * 4 + r;
                        if (p < 120) {
                            unsigned lo = (unsigned)(unsigned short)f2b(fmaxf(acc1[i][0][r] + b4[0], 0.f))
                                        | ((unsigned)(unsigned short)f2b(fmaxf(acc1[i][1][r] + b4[1], 0.f)) << 16);
                            unsigned hi = (unsigned)(unsigned short)f2b(fmaxf(acc1[i][2][r] + b4[2], 0.f))
                                        | ((unsigned)(unsigned short)f2b(fmaxf(acc1[i][3][r] + b4[3], 0.f)) << 16);
                            *reinterpret_cast<uint2*>(&s_Y1[p * 72 + ml * 4]) = make_uint2(lo, hi);
                        }
                    }
            }
            __syncthreads();
        }
    }

    // ================= conv2: 3x3, Y1 -> Y2 10x8x64 =================
    {
        int prowA, pcolA, prowB, pcolB;
        {
            int p0 = wv * 16 + ml; prowA = p0 >> 3; pcolA = p0 & 7;
            int p1 = 64 + ml;      prowB = p1 >> 3; pcolB = p1 & 7;
        }
        floatx4 acc2[4] = {};
        floatx4 acc2t = {};

#pragma unroll
        for (int t = 0; t < 9; ++t) {
            dma(8 + t);  // phases 8..16 (16 = conv3 ksteps 0-1)
            const short* sb = s_B[(7 + t) & 1];
#pragma unroll
            for (int kb = 0; kb < 2; ++kb) {
                const int kk = t * 2 + kb;
                bf16x8 Bf[4];
#pragma unroll
                for (int j2 = 0; j2 < 4; ++j2)
                    Bf[j2] = *reinterpret_cast<const bf16x8*>(&sb[kb * 2048 + (j2 * 64 + lane) * 8]);
                // 5th-tile B frag re-read with wave-uniform address (rule #20:
                // Bf[wv] with runtime wv would spill the array to scratch)
                bf16x8 B4 = *reinterpret_cast<const bf16x8*>(&sb[kb * 2048 + (wv * 64 + lane) * 8]);
                const int tap = kk >> 1;
                const int chb = (kk & 1) * 32 + q * 8;
                const int dx = tap / 3, dy = tap - (tap / 3) * 3;
                bf16x8 A0 = *reinterpret_cast<const bf16x8*>(
                    &s_Y1[((prowA + dx) * 10 + (pcolA + dy)) * 72 + chb]);
                bf16x8 A4 = *reinterpret_cast<const bf16x8*>(
                    &s_Y1[((prowB + dx) * 10 + (pcolB + dy)) * 72 + chb]);
                __builtin_amdgcn_s_setprio(1);
#pragma unroll
                for (int j2 = 0; j2 < 4; ++j2)
                    acc2[j2] = __builtin_amdgcn_mfma_f32_16x16x32_bf16(A0, Bf[j2], acc2[j2], 0, 0, 0);
                acc2t = __builtin_amdgcn_mfma_f32_16x16x32_bf16(A4, B4, acc2t, 0, 0, 0);
                __builtin_amdgcn_s_setprio(0);
            }
            if (t == 8) {  // epilogue into s_u (X is dead)
                float b4[4];
#pragma unroll
                for (int j2 = 0; j2 < 4; ++j2) b4[j2] = bc2[j2 * 16 + ml];
#pragma unroll
                for (int r = 0; r < 4; ++r) {
                    int p = wv * 16 + q * 4 + r;
                    unsigned lo = (unsigned)(unsigned short)f2b(fmaxf(acc2[0][r] + b4[0], 0.f))
                                | ((unsigned)(unsigned short)f2b(fmaxf(acc2[1][r] + b4[1], 0.f)) << 16);
                    unsigned hi = (unsigned)(unsigned short)f2b(fmaxf(acc2[2][r] + b4[2], 0.f))
                                | ((unsigned)(unsigned short)f2b(fmaxf(acc2[3][r] + b4[3], 0.f)) << 16);
                    *reinterpret_cast<uint2*>(&s_u[p * 72 + ml * 4]) = make_uint2(lo, hi);
                }
                float bt = bc2[wv * 16 + ml];
#pragma unroll
                for (int r = 0; r < 4; ++r) {
                    int p = 64 + q * 4 + r;
                    s_u[p * 72 + ml * 4 + wv] = f2b(fmaxf(acc2t[r] + bt, 0.f));
                }
                if (tid < 64) s_feat[tid] = 0.f;
            }
            __syncthreads();
        }
    }

    // ====== conv3: 3x3, Y2 -> 8x6 masked room-sum (waves 0-2) ======
    {
        int prow3, pcol3;
        {
            int p0 = wv * 16 + ml;
            prow3 = p0 / 6; pcol3 = p0 - prow3 * 6;
        }
        floatx4 acc3[4] = {};

#pragma unroll
        for (int t = 0; t < 9; ++t) {
            if (t < 8) dma(17 + t);  // phases 17..24
            const short* sb = s_B[(16 + t) & 1];
            if (wv < 3) {
#pragma unroll
                for (int kb = 0; kb < 2; ++kb) {
                    const int kk = t * 2 + kb;
                    bf16x8 Bf[4];
#pragma unroll
                    for (int j2 = 0; j2 < 4; ++j2)
                        Bf[j2] = *reinterpret_cast<const bf16x8*>(&sb[kb * 2048 + (j2 * 64 + lane) * 8]);
                    const int tap = kk >> 1;
                    const int chb = (kk & 1) * 32 + q * 8;
                    const int dx = tap / 3, dy = tap - (tap / 3) * 3;
                    bf16x8 A = *reinterpret_cast<const bf16x8*>(
                        &s_u[((prow3 + dx) * 8 + (pcol3 + dy)) * 72 + chb]);
                    __builtin_amdgcn_s_setprio(1);
#pragma unroll
                    for (int j2 = 0; j2 < 4; ++j2)
                        acc3[j2] = __builtin_amdgcn_mfma_f32_16x16x32_bf16(A, Bf[j2], acc3[j2], 0, 0, 0);
                    __builtin_amdgcn_s_setprio(0);
                }
            }
            if (t == 8 && wv < 3) {  // masked reduce
                float b4[4];
#pragma unroll
                for (int j2 = 0; j2 < 4; ++j2) b4[j2] = bc3[j2 * 16 + ml];
                float part[4] = {0.f, 0.f, 0.f, 0.f};
                const unsigned long long mk = rmask[room];
#pragma unroll
                for (int r = 0; r < 4; ++r) {
                    int p = wv * 16 + q * 4 + r;  // == w*6+h == mask bit index
                    if ((mk >> p) & 1ull) {
#pragma unroll
                        for (int j2 = 0; j2 < 4; ++j2)
                            part[j2] += fmaxf(acc3[j2][r] + b4[j2], 0.f);
                    }
                }
#pragma unroll
                for (int j2 = 0; j2 < 4; ++j2) {
                    part[j2] += __shfl_xor(part[j2], 16);
                    part[j2] += __shfl_xor(part[j2], 32);
                }
                if (q == 0) {
#pragma unroll
                    for (int j2 = 0; j2 < 4; ++j2)
                        atomicAdd(&s_feat[j2 * 16 + ml], part[j2]);  // 3 contenders
                }
            }
            __syncthreads();
        }
    }

    if (tid < 64)
        feat[((size_t)n * RR + room) * 64 + tid] = s_feat[tid];
}

// ---------------------------------------------------------------------------
// Per-sample head: room MLP (64->128->128), room-sum, fc1, fc2.
// FEAT holds unnormalized masked sums; normalize by rinv here.
// ---------------------------------------------------------------------------
__global__ __launch_bounds__(256) void mlp_head(const float* __restrict__ feat,
                                                const float* __restrict__ HEAD,
                                                const float* __restrict__ rinv,
                                                const float* __restrict__ b1,
                                                const float* __restrict__ b2,
                                                const float* __restrict__ bf1,
                                                const float* __restrict__ bf2,
                                                float* __restrict__ outp)
{
    __shared__ __align__(16) float s_feat[RR * 64];
    __shared__ __align__(16) float s_h1[RR * 128];
    __shared__ __align__(16) float s_s[2 * 128];
    __shared__ __align__(16) float s_sf[128];
    __shared__ __align__(16) float s_t1[256];

    const int n = blockIdx.x;
    const int tid = threadIdx.x;
    const float* W1t = HEAD + F_WR1T;
    const float* W2t = HEAD + F_WR2T;
    const float* F1t = HEAD + F_F1T;
    const float* F2t = HEAD + F_F2T;

    for (int i = tid; i < RR * 64; i += 256)
        s_feat[i] = feat[(size_t)n * RR * 64 + i] * rinv[i >> 6];
    __syncthreads();

    const int o = tid & 127;
    const int rh = tid >> 7;

    float acc[16];
#pragma unroll
    for (int r = 0; r < 16; ++r) acc[r] = b1[o];
    for (int c4 = 0; c4 < 16; ++c4) {
        float w0 = W1t[(c4 * 4 + 0) * 128 + o];
        float w1 = W1t[(c4 * 4 + 1) * 128 + o];
        float w2 = W1t[(c4 * 4 + 2) * 128 + o];
        float w3 = W1t[(c4 * 4 + 3) * 128 + o];
#pragma unroll
        for (int r = 0; r < 16; ++r) {
            float4 f = *reinterpret_cast<const float4*>(&s_feat[(rh * 16 + r) * 64 + c4 * 4]);
            acc[r] += f.x * w0 + f.y * w1 + f.z * w2 + f.w * w3;
        }
    }
#pragma unroll
    for (int r = 0; r < 16; ++r) s_h1[(rh * 16 + r) * 128 + o] = fmaxf(acc[r], 0.f);
    __syncthreads();

#pragma unroll
    for (int r = 0; r < 16; ++r) acc[r] = b2[o];
    for (int c4 = 0; c4 < 32; ++c4) {
        float w0 = W2t[(c4 * 4 + 0) * 128 + o];
        float w1 = W2t[(c4 * 4 + 1) * 128 + o];
        float w2 = W2t[(c4 * 4 + 2) * 128 + o];
        float w3 = W2t[(c4 * 4 + 3) * 128 + o];
#pragma unroll
        for (int r = 0; r < 16; ++r) {
            float4 f = *reinterpret_cast<const float4*>(&s_h1[(rh * 16 + r) * 128 + c4 * 4]);
            acc[r] += f.x * w0 + f.y * w1 + f.z * w2 + f.w * w3;
        }
    }
    float ps = 0.f;
#pragma unroll
    for (int r = 0; r < 16; ++r) ps += fmaxf(acc[r], 0.f);
    s_s[rh * 128 + o] = ps;
    __syncthreads();
    if (tid < 128) s_sf[tid] = s_s[tid] + s_s[128 + tid];
    __syncthreads();

    {
        float a = bf1[tid];
        for (int c4 = 0; c4 < 32; ++c4) {
            float4 f = *reinterpret_cast<const float4*>(&s_sf[c4 * 4]);
            a += f.x * F1t[(c4 * 4 + 0) * 256 + tid];
            a += f.y * F1t[(c4 * 4 + 1) * 256 + tid];
            a += f.z * F1t[(c4 * 4 + 2) * 256 + tid];
            a += f.w * F1t[(c4 * 4 + 3) * 256 + tid];
        }
        s_t1[tid] = fmaxf(a, 0.f);
    }
    __syncthreads();

    {
        float a = bf2[tid];
        for (int c4 = 0; c4 < 64; ++c4) {
            float4 f = *reinterpret_cast<const float4*>(&s_t1[c4 * 4]);
            a += f.x * F2t[(c4 * 4 + 0) * 256 + tid];
            a += f.y * F2t[(c4 * 4 + 1) * 256 + tid];
            a += f.z * F2t[(c4 * 4 + 2) * 256 + tid];
            a += f.w * F2t[(c4 * 4 + 3) * 256 + tid];
        }
        outp[(size_t)n * 256 + tid] = a;
    }
}

// ---------------------------------------------------------------------------
extern "C" void kernel_launch(void* const* d_in, const int* in_sizes, int n_in,
                              void* d_out, int out_size, void* d_ws, size_t ws_size,
                              hipStream_t stream)
{
    const int* pos = (const int*)d_in[0];
    const float* rt = (const float*)d_in[1];
    const float* emb = (const float*)d_in[2];
    const float* w1 = (const float*)d_in[3];
    const float* bc1 = (const float*)d_in[4];
    const float* w2 = (const float*)d_in[5];
    const float* bc2 = (const float*)d_in[6];
    const float* w3 = (const float*)d_in[7];
    const float* bc3 = (const float*)d_in[8];
    const float* wr1 = (const float*)d_in[9];
    const float* br1 = (const float*)d_in[10];
    const float* wr2 = (const float*)d_in[11];
    const float* br2 = (const float*)d_in[12];
    const float* wf1 = (const float*)d_in[13];
    const float* bf1 = (const float*)d_in[14];
    const float* wf2 = (const float*)d_in[15];
    const float* bf2 = (const float*)d_in[16];
    float* out = (float*)d_out;
    char* ws = (char*)d_ws;

    prep_weights<<<880, 256, 0, stream>>>(w1, w2, w3, wr1, wr2, wf1, wf2, ws);
    prep_rooms<<<1, 64, 0, stream>>>(rt, ws);

    // largest batch chunk whose X buffer fits the workspace
    int nc = 16;
    const int cands[4] = {256, 128, 64, 32};
    for (int k = 0; k < 4; ++k) {
        size_t need = B_CHUNK + (size_t)cands[k] * PERN_BYTES;
        if (need <= ws_size) { nc = cands[k]; break; }
    }

    const short* WALL = (const short*)(ws + B_W1F);
    const unsigned long long* RMASK = (const unsigned long long*)(ws + B_RAUX);
    const float* RINV = (const float*)(ws + B_RINV);
    float* HEAD = (float*)(ws + B_HEAD);
    float* FEAT = (float*)(ws + B_FEAT);
    short* Xc = (short*)(ws + B_CHUNK);

    for (int n0 = 0; n0 < NB; n0 += nc) {
        build_x<<<dim3(21, nc), 256, 0, stream>>>(pos, rt, emb, Xc, n0);
        fused_conv<<<dim3(RR, nc), 256, 0, stream>>>(Xc, WALL, bc1, bc2, bc3,
                                                     pos, RMASK, FEAT, n0);
    }

    mlp_head<<<NB, 256, 0, stream>>>(FEAT, HEAD, RINV, br1, br2, bf1, bf2, out);
}

// Round 5
// 303.363 us; speedup vs baseline: 2.2645x; 1.0328x over previous
//
#include <hip/hip_runtime.h>
#include <hip/hip_bf16.h>
#include <cstddef>

// Problem constants
#define NB 256   // batch
#define RR 32    // rooms
#define WW 8     // room width
#define HH 6     // room height
#define MXY 72   // map extent
#define EMB 6
#define CIN1 16  // 9 + 1 + 6

typedef __bf16 bf16x8 __attribute__((ext_vector_type(8)));
typedef float floatx4 __attribute__((ext_vector_type(4)));

// --- Workspace layout (byte offsets) ---------------------------------------
// Conv weights are packed as 25 contiguous 8KB "phases":
//   W1F: 7 phases (14 ksteps)  [0,57344)
//   W2F: 9 phases (18 ksteps)  [57344,131072)
//   W3F: 9 phases (18 ksteps)  [131072,204800)
static const size_t B_W1F  = 0;
static const size_t B_W2F  = 57344;
static const size_t B_W3F  = 131072;
static const size_t B_RAUX = 204800;    // room masks (32 u64)
static const size_t B_RINV = 205056;    // 1/room_size (32 f32)
static const size_t B_HEAD = 205312;    // fp32 head weights, 122880 floats
static const size_t F_WR1T = 0;         // (64,128)
static const size_t F_WR2T = 8192;      // (128,128)
static const size_t F_F1T  = 24576;     // (128,256)
static const size_t F_F2T  = 57344;     // (256,256)
static const size_t B_FEAT = 696832;    // (256,32,64) f32 = 2 MB
static const size_t B_CHUNK = 2793984;  // X buffer
static const size_t PERN_BYTES = 165888;  // X bf16 5184*16*2

__device__ inline short f2b(float f) {
    unsigned u = __builtin_bit_cast(unsigned, f);
    unsigned r = (u + 0x7fffu + ((u >> 16) & 1u)) >> 16;
    return (short)r;
}

// ---------------------------------------------------------------------------
// Prep: conv weights fp32 -> bf16 B-fragment order; head weights transposed.
// Fragment order: [kk][ntile][lane][j] ; virtual k = kk*32 + (lane>>4)*8 + j
// oc = ntile*16 + (lane&15).
// conv1: (tap,ci) natural. conv2/3: position cp -> channel (cp>>2)+(cp&3)*16
// (paired-channel layout Y1/Y2 are written in).
// ---------------------------------------------------------------------------
__global__ void prep_weights(const float* __restrict__ w1, const float* __restrict__ w2,
                             const float* __restrict__ w3, const float* __restrict__ wr1,
                             const float* __restrict__ wr2, const float* __restrict__ wf1,
                             const float* __restrict__ wf2, char* __restrict__ ws)
{
    short* W1F = (short*)(ws + B_W1F);
    short* W2F = (short*)(ws + B_W2F);
    short* W3F = (short*)(ws + B_W3F);
    float* HEAD = (float*)(ws + B_HEAD);

    int idx = blockIdx.x * 256 + threadIdx.x;
    if (idx < 28672) {  // conv1: 14 ksteps (padded), CIN=16, taps 0..24 real
        int j = idx & 7, lane = (idx >> 3) & 63, nt = (idx >> 9) & 3, kk = idx >> 11;
        int k = kk * 32 + (lane >> 4) * 8 + j;
        int oc = nt * 16 + (lane & 15);
        int tap = k >> 4, ci = k & 15;
        float v = (tap < 25) ? w1[(oc * 16 + ci) * 25 + tap] : 0.f;
        W1F[idx] = f2b(v);
        return;
    }
    idx -= 28672;
    if (idx < 36864) {  // conv2: 18 ksteps, CIN=64, 9 taps, permuted ci
        int j = idx & 7, lane = (idx >> 3) & 63, nt = (idx >> 9) & 3, kk = idx >> 11;
        int k = kk * 32 + (lane >> 4) * 8 + j;
        int oc = nt * 16 + (lane & 15);
        int tap = k >> 6, cp = k & 63;
        int ci = (cp >> 2) + (cp & 3) * 16;
        W2F[idx] = f2b(w2[(oc * 64 + ci) * 9 + tap]);
        return;
    }
    idx -= 36864;
    if (idx < 36864) {  // conv3, permuted ci
        int j = idx & 7, lane = (idx >> 3) & 63, nt = (idx >> 9) & 3, kk = idx >> 11;
        int k = kk * 32 + (lane >> 4) * 8 + j;
        int oc = nt * 16 + (lane & 15);
        int tap = k >> 6, cp = k & 63;
        int ci = (cp >> 2) + (cp & 3) * 16;
        W3F[idx] = f2b(w3[(oc * 64 + ci) * 9 + tap]);
        return;
    }
    idx -= 36864;
    if (idx < 8192)  { int o = idx & 127, c = idx >> 7; HEAD[F_WR1T + idx] = wr1[o * 64 + c]; return; }
    idx -= 8192;
    if (idx < 16384) { int o = idx & 127, c = idx >> 7; HEAD[F_WR2T + idx] = wr2[o * 128 + c]; return; }
    idx -= 16384;
    if (idx < 32768) { int o = idx & 255, c = idx >> 8; HEAD[F_F1T + idx] = wf1[o * 128 + c]; return; }
    idx -= 32768;
    if (idx < 65536) { int o = idx & 255, c = idx >> 8; HEAD[F_F2T + idx] = wf2[o * 256 + c]; return; }
}

// Room footprint bitmasks (48 bits) + 1/room_size.
__global__ void prep_rooms(const float* __restrict__ rt, char* __restrict__ ws)
{
    int r = threadIdx.x;
    if (r >= RR) return;
    unsigned long long m = 0ull;
    int cnt = 0;
    for (int j = 0; j < WW * HH; ++j)
        if (rt[r * 9 * 48 + j] != 0.f) { m |= (1ull << j); ++cnt; }
    ((unsigned long long*)(ws + B_RAUX))[r] = m;
    ((float*)(ws + B_RINV))[r] = 1.f / (float)cnt;
}

// ---------------------------------------------------------------------------
// Build X (nc, 72, 72, 16) NHWC bf16 — GATHER style.
// ---------------------------------------------------------------------------
__global__ __launch_bounds__(256) void build_x(const int* __restrict__ pos,
                                               const float* __restrict__ rt,
                                               const float* __restrict__ emb,
                                               short* __restrict__ X, int n0)
{
    const int nl = blockIdx.y;
    const int n = n0 + nl;
    const int p = blockIdx.x * 256 + threadIdx.x;

    __shared__ int s_px[RR], s_py[RR];
    __shared__ float s_emb[RR * EMB];
    if (threadIdx.x < RR) {
        s_px[threadIdx.x] = pos[(n * RR + threadIdx.x) * 2 + 0];
        s_py[threadIdx.x] = pos[(n * RR + threadIdx.x) * 2 + 1];
    }
    for (int i = threadIdx.x; i < RR * EMB; i += 256) s_emb[i] = emb[i];
    __syncthreads();
    if (p >= MXY * MXY) return;

    const int gx = p / MXY, gy = p - (p / MXY) * MXY;

    float acc[16];
#pragma unroll
    for (int c = 0; c < 16; ++c) acc[c] = 0.f;
    acc[9] = 1.f;

    for (int r = 0; r < RR; ++r) {
        int w = gx - s_px[r], h = gy - s_py[r];
        if ((unsigned)w < (unsigned)WW && (unsigned)h < (unsigned)HH) {
            int j = w * HH + h;
            const float* rr = rt + r * 9 * 48;
#pragma unroll
            for (int c = 0; c < 9; ++c) acc[c] += rr[c * 48 + j];
            float m = rr[j];  // channel 0 = room_map
#pragma unroll
            for (int e = 0; e < EMB; ++e) acc[10 + e] += s_emb[r * EMB + e] * m;
        }
    }

    short o[16];
#pragma unroll
    for (int c = 0; c < 16; ++c) o[c] = f2b(acc[c]);
    short* dst = X + ((size_t)nl * (MXY * MXY) + p) * CIN1;
    *reinterpret_cast<uint4*>(dst) = *reinterpret_cast<uint4*>(o);
    *reinterpret_cast<uint4*>(dst + 8) = *reinterpret_cast<uint4*>(o + 8);
}

// ---------------------------------------------------------------------------
// ROUND-5 FUSED CONV CHAIN, 2 SAMPLES PER BLOCK.
//
// Round-4 diagnosis: LDS instruction throughput is the wall. Per-wave B-frag
// reads (4/kstep, identical across waves) were 47% of all LDS reads; conv3's
// MFMA:read cycle ratio was 19:60. Fix: block = (room, sample-pair). Each
// wave owns m-tiles from TWO samples -> every B read feeds 2x the MFMAs:
//   conv1: 16 m-slots (8/sample), 4/wave ; per kstep 4B+4A reads, 16 MFMA
//   conv2: 12 m-slots (5+1 dummy per sample), 3/wave ; 4B+3A, 12 MFMA
//   conv3: 8 m-slots (3+1 dummy per sample), 2/wave ; 4B+2A, 8 MFMA
// Per-block LDS reads: 1384 for 2 samples (was 2x1100); barriers & weight
// DMA per unit work halved. Weight-phase DMA pipeline unchanged (25 x 8KB).
//
// LDS: Y1 2x17280 + u 2x11520 + s_B 16384 + feat 512 = 74.5 KB -> 2 blk/CU.
// ---------------------------------------------------------------------------
__global__ __launch_bounds__(256, 2) void fused_conv(const short* __restrict__ X,
    const short* __restrict__ wAll, const float* __restrict__ bc1,
    const float* __restrict__ bc2, const float* __restrict__ bc3,
    const int* __restrict__ pos, const unsigned long long* __restrict__ rmask,
    float* __restrict__ feat, int n0)
{
    __shared__ __align__(16) short s_Y1[2 * 8640];   // [smp][120px][72], paired-ch
    __shared__ __align__(16) short s_u[2 * 5760];    // X [smp][224][24] then Y2 [smp][80][72]
    __shared__ __align__(16) short s_B[2][4096];     // weight phase double-buffer
    __shared__ float s_feat[2][64];

    const int tid = threadIdx.x;
    const int lane = tid & 63;
    const int wv = tid >> 6;
    const int ml = lane & 15;
    const int q = lane >> 4;
    const int room = blockIdx.x;
    const int pair = blockIdx.y;
    const int lA = 2 * pair;          // local sample indices lA, lA+1
    const int nA = n0 + lA;           // global sample indices

    const int pxA = pos[(nA * RR + room) * 2 + 0];
    const int pyA = pos[(nA * RR + room) * 2 + 1];
    const int pxB = pos[((nA + 1) * RR + room) * 2 + 0];
    const int pyB = pos[((nA + 1) * RR + room) * 2 + 1];

    const char* wB = (const char*)wAll;
    // DMA one 8KB weight phase into its parity buffer (2KB per wave, 2x1KB)
    auto dma = [&](int ph) {
        const char* src = wB + (size_t)ph * 8192 + wv * 2048 + lane * 16;
        short* d0 = &s_B[ph & 1][wv * 1024];
        __builtin_amdgcn_global_load_lds(
            (const __attribute__((address_space(1))) unsigned int*)src,
            (__attribute__((address_space(3))) unsigned int*)d0, 16, 0, 0);
        __builtin_amdgcn_global_load_lds(
            (const __attribute__((address_space(1))) unsigned int*)(src + 1024),
            (__attribute__((address_space(3))) unsigned int*)(d0 + 512), 16, 0, 0);
    };

    dma(0);

    // ---- stage X tiles for both samples (16x14 px, zero-padded halo) ----
    for (int i = tid; i < 896; i += 256) {
        int smp = (i >= 448);
        int ii = i - (smp ? 448 : 0);
        int half = ii & 1, pix = ii >> 1;
        int row = pix / 14, col = pix - row * 14;
        int gx = (smp ? pxB : pxA) - 4 + row;
        int gy = (smp ? pyB : pyA) - 4 + col;
        const short* Xn = X + (size_t)(lA + smp) * (MXY * MXY) * CIN1;
        uint4 v = make_uint4(0u, 0u, 0u, 0u);
        if ((unsigned)gx < (unsigned)MXY && (unsigned)gy < (unsigned)MXY)
            v = *reinterpret_cast<const uint4*>(Xn + ((size_t)gx * MXY + gy) * CIN1 + half * 8);
        *reinterpret_cast<uint4*>(&s_u[smp * 5760 + pix * 24 + half * 8]) = v;
    }
    __syncthreads();  // X staged, weight phase 0 resident

    // ================= conv1: 5x5, X(16ch) -> Y1 12x10x64 (x2) ============
    {
        // slot s = wv + 4k : smp = s>>3, tile t = s&7 (tile 7 partially padded)
        int pr1[4], pc1[4], sm1[4];
#pragma unroll
        for (int k = 0; k < 4; ++k) {
            int s = wv + 4 * k;
            int t = s & 7;
            int p = t * 16 + ml;
            if (p > 119) p = 119;  // pad px: duplicate compute, discarded
            pr1[k] = p / 10; pc1[k] = p - (p / 10) * 10;
            sm1[k] = (s >> 3) * 5760;
        }
        floatx4 acc1[4][4] = {};

#pragma unroll
        for (int t7 = 0; t7 < 7; ++t7) {
            dma(t7 + 1);  // phases 1..7 (7 = conv2 ksteps 0-1)
            const short* sb = s_B[t7 & 1];
#pragma unroll
            for (int kb = 0; kb < 2; ++kb) {
                const int kk = t7 * 2 + kb;
                bf16x8 Bf[4];
#pragma unroll
                for (int j2 = 0; j2 < 4; ++j2)
                    Bf[j2] = *reinterpret_cast<const bf16x8*>(&sb[kb * 2048 + (j2 * 64 + lane) * 8]);
                int tap = kk * 2 + (q >> 1);
                if (tap > 24) tap = 24;  // padded-tail weights are zero
                const int chb = (q & 1) * 8;
                const int dx = tap / 5, dy = tap - (tap / 5) * 5;
                __builtin_amdgcn_s_setprio(1);
#pragma unroll
                for (int k = 0; k < 4; ++k) {
                    bf16x8 A = *reinterpret_cast<const bf16x8*>(
                        &s_u[sm1[k] + ((pr1[k] + dx) * 14 + (pc1[k] + dy)) * 24 + chb]);
#pragma unroll
                    for (int j2 = 0; j2 < 4; ++j2)
                        acc1[k][j2] = __builtin_amdgcn_mfma_f32_16x16x32_bf16(
                            A, Bf[j2], acc1[k][j2], 0, 0, 0);
                }
                __builtin_amdgcn_s_setprio(0);
            }
            if (t7 == 6) {  // epilogue: bias+relu, b64 paired-channel stores
                float b4[4];
#pragma unroll
                for (int j2 = 0; j2 < 4; ++j2) b4[j2] = bc1[j2 * 16 + ml];
#pragma unroll
                for (int k = 0; k < 4; ++k) {
                    int s = wv + 4 * k;
                    int t = s & 7;
                    int sy = (s >> 3) * 8640;
#pragma unroll
                    for (int r = 0; r < 4; ++r) {
                        int p = t * 16 + q * 4 + r;
                        if (p < 120) {
                            unsigned lo = (unsigned)(unsigned short)f2b(fmaxf(acc1[k][0][r] + b4[0], 0.f))
                                        | ((unsigned)(unsigned short)f2b(fmaxf(acc1[k][1][r] + b4[1], 0.f)) << 16);
                            unsigned hi = (unsigned)(unsigned short)f2b(fmaxf(acc1[k][2][r] + b4[2], 0.f))
                                        | ((unsigned)(unsigned short)f2b(fmaxf(acc1[k][3][r] + b4[3], 0.f)) << 16);
                            *reinterpret_cast<uint2*>(&s_Y1[sy + p * 72 + ml * 4]) = make_uint2(lo, hi);
                        }
                    }
                }
            }
            __syncthreads();
        }
    }

    // ================= conv2: 3x3, Y1 -> Y2 10x8x64 (x2) ==================
    {
        // slot s = wv + 4k (k=0..2): smp = s/6, tile t = s%6 (t==5 dummy)
        int prA[3], pcA[3], smY[3], smU[3], t2[3];
#pragma unroll
        for (int k = 0; k < 3; ++k) {
            int s = wv + 4 * k;
            int sm = s / 6;
            int t = s - sm * 6;
            int te = (t == 5) ? 4 : t;
            int p = te * 16 + ml;
            prA[k] = p >> 3; pcA[k] = p & 7;
            smY[k] = sm * 8640;
            smU[k] = sm * 5760;
            t2[k] = t;
        }
        floatx4 acc2[3][4] = {};

#pragma unroll
        for (int t9 = 0; t9 < 9; ++t9) {
            dma(8 + t9);  // phases 8..16 (16 = conv3 ksteps 0-1)
            const short* sb = s_B[(7 + t9) & 1];
#pragma unroll
            for (int kb = 0; kb < 2; ++kb) {
                const int kk = t9 * 2 + kb;
                bf16x8 Bf[4];
#pragma unroll
                for (int j2 = 0; j2 < 4; ++j2)
                    Bf[j2] = *reinterpret_cast<const bf16x8*>(&sb[kb * 2048 + (j2 * 64 + lane) * 8]);
                const int tap = kk >> 1;
                const int chb = (kk & 1) * 32 + q * 8;
                const int dx = tap / 3, dy = tap - (tap / 3) * 3;
                __builtin_amdgcn_s_setprio(1);
#pragma unroll
                for (int k = 0; k < 3; ++k) {
                    bf16x8 A = *reinterpret_cast<const bf16x8*>(
                        &s_Y1[smY[k] + ((prA[k] + dx) * 10 + (pcA[k] + dy)) * 72 + chb]);
#pragma unroll
                    for (int j2 = 0; j2 < 4; ++j2)
                        acc2[k][j2] = __builtin_amdgcn_mfma_f32_16x16x32_bf16(
                            A, Bf[j2], acc2[k][j2], 0, 0, 0);
                }
                __builtin_amdgcn_s_setprio(0);
            }
            if (t9 == 8) {  // epilogue into s_u (X is dead)
                float b4[4];
#pragma unroll
                for (int j2 = 0; j2 < 4; ++j2) b4[j2] = bc2[j2 * 16 + ml];
#pragma unroll
                for (int k = 0; k < 3; ++k) {
                    if (t2[k] != 5) {  // wave-uniform
#pragma unroll
                        for (int r = 0; r < 4; ++r) {
                            int p = t2[k] * 16 + q * 4 + r;
                            unsigned lo = (unsigned)(unsigned short)f2b(fmaxf(acc2[k][0][r] + b4[0], 0.f))
                                        | ((unsigned)(unsigned short)f2b(fmaxf(acc2[k][1][r] + b4[1], 0.f)) << 16);
                            unsigned hi = (unsigned)(unsigned short)f2b(fmaxf(acc2[k][2][r] + b4[2], 0.f))
                                        | ((unsigned)(unsigned short)f2b(fmaxf(acc2[k][3][r] + b4[3], 0.f)) << 16);
                            *reinterpret_cast<uint2*>(&s_u[smU[k] + p * 72 + ml * 4]) = make_uint2(lo, hi);
                        }
                    }
                }
                if (tid < 128) s_feat[tid >> 6][tid & 63] = 0.f;
            }
            __syncthreads();
        }
    }

    // ====== conv3: 3x3, Y2 -> 8x6 masked room-sum (x2) ======
    {
        // slot s = wv + 4k (k=0..1): smp = s>>2, tile t = s&3 (t==3 dummy)
        int pr3[2], pc3[2], smU3[2], smF3[2], t3[2];
#pragma unroll
        for (int k = 0; k < 2; ++k) {
            int s = wv + 4 * k;
            int sm = s >> 2;
            int t = s & 3;
            int te = (t == 3) ? 2 : t;
            int p = te * 16 + ml;
            pr3[k] = p / 6; pc3[k] = p - (p / 6) * 6;
            smU3[k] = sm * 5760;
            smF3[k] = sm;
            t3[k] = t;
        }
        floatx4 acc3[2][4] = {};

#pragma unroll
        for (int t9 = 0; t9 < 9; ++t9) {
            if (t9 < 8) dma(17 + t9);  // phases 17..24
            const short* sb = s_B[(16 + t9) & 1];
#pragma unroll
            for (int kb = 0; kb < 2; ++kb) {
                const int kk = t9 * 2 + kb;
                bf16x8 Bf[4];
#pragma unroll
                for (int j2 = 0; j2 < 4; ++j2)
                    Bf[j2] = *reinterpret_cast<const bf16x8*>(&sb[kb * 2048 + (j2 * 64 + lane) * 8]);
                const int tap = kk >> 1;
                const int chb = (kk & 1) * 32 + q * 8;
                const int dx = tap / 3, dy = tap - (tap / 3) * 3;
                __builtin_amdgcn_s_setprio(1);
#pragma unroll
                for (int k = 0; k < 2; ++k) {
                    bf16x8 A = *reinterpret_cast<const bf16x8*>(
                        &s_u[smU3[k] + ((pr3[k] + dx) * 8 + (pc3[k] + dy)) * 72 + chb]);
#pragma unroll
                    for (int j2 = 0; j2 < 4; ++j2)
                        acc3[k][j2] = __builtin_amdgcn_mfma_f32_16x16x32_bf16(
                            A, Bf[j2], acc3[k][j2], 0, 0, 0);
                }
                __builtin_amdgcn_s_setprio(0);
            }
            if (t9 < 8) __syncthreads();
        }

        // masked room-sum reduce (mask bit index == pixel index w*6+h)
        float b4[4];
#pragma unroll
        for (int j2 = 0; j2 < 4; ++j2) b4[j2] = bc3[j2 * 16 + ml];
        const unsigned long long mk = rmask[room];
#pragma unroll
        for (int k = 0; k < 2; ++k) {
            if (t3[k] != 3) {  // wave-uniform
                float part[4] = {0.f, 0.f, 0.f, 0.f};
#pragma unroll
                for (int r = 0; r < 4; ++r) {
                    int p = t3[k] * 16 + q * 4 + r;
                    if ((mk >> p) & 1ull) {
#pragma unroll
                        for (int j2 = 0; j2 < 4; ++j2)
                            part[j2] += fmaxf(acc3[k][j2][r] + b4[j2], 0.f);
                    }
                }
#pragma unroll
                for (int j2 = 0; j2 < 4; ++j2) {
                    part[j2] += __shfl_xor(part[j2], 16);
                    part[j2] += __shfl_xor(part[j2], 32);
                }
                if (q == 0) {
#pragma unroll
                    for (int j2 = 0; j2 < 4; ++j2)
                        atomicAdd(&s_feat[smF3[k]][j2 * 16 + ml], part[j2]);  // 3 contenders
                }
            }
        }
    }
    __syncthreads();

    if (tid < 128)
        feat[((size_t)(nA + (tid >> 6)) * RR + room) * 64 + (tid & 63)] =
            s_feat[tid >> 6][tid & 63];
}

// ---------------------------------------------------------------------------
// Per-sample head: room MLP (64->128->128), room-sum, fc1, fc2.
// FEAT holds unnormalized masked sums; normalize by rinv here.
// ---------------------------------------------------------------------------
__global__ __launch_bounds__(256) void mlp_head(const float* __restrict__ feat,
                                                const float* __restrict__ HEAD,
                                                const float* __restrict__ rinv,
                                                const float* __restrict__ b1,
                                                const float* __restrict__ b2,
                                                const float* __restrict__ bf1,
                                                const float* __restrict__ bf2,
                                                float* __restrict__ outp)
{
    __shared__ __align__(16) float s_feat[RR * 64];
    __shared__ __align__(16) float s_h1[RR * 128];
    __shared__ __align__(16) float s_s[2 * 128];
    __shared__ __align__(16) float s_sf[128];
    __shared__ __align__(16) float s_t1[256];

    const int n = blockIdx.x;
    const int tid = threadIdx.x;
    const float* W1t = HEAD + F_WR1T;
    const float* W2t = HEAD + F_WR2T;
    const float* F1t = HEAD + F_F1T;
    const float* F2t = HEAD + F_F2T;

    for (int i = tid; i < RR * 64; i += 256)
        s_feat[i] = feat[(size_t)n * RR * 64 + i] * rinv[i >> 6];
    __syncthreads();

    const int o = tid & 127;
    const int rh = tid >> 7;

    float acc[16];
#pragma unroll
    for (int r = 0; r < 16; ++r) acc[r] = b1[o];
    for (int c4 = 0; c4 < 16; ++c4) {
        float w0 = W1t[(c4 * 4 + 0) * 128 + o];
        float w1 = W1t[(c4 * 4 + 1) * 128 + o];
        float w2 = W1t[(c4 * 4 + 2) * 128 + o];
        float w3 = W1t[(c4 * 4 + 3) * 128 + o];
#pragma unroll
        for (int r = 0; r < 16; ++r) {
            float4 f = *reinterpret_cast<const float4*>(&s_feat[(rh * 16 + r) * 64 + c4 * 4]);
            acc[r] += f.x * w0 + f.y * w1 + f.z * w2 + f.w * w3;
        }
    }
#pragma unroll
    for (int r = 0; r < 16; ++r) s_h1[(rh * 16 + r) * 128 + o] = fmaxf(acc[r], 0.f);
    __syncthreads();

#pragma unroll
    for (int r = 0; r < 16; ++r) acc[r] = b2[o];
    for (int c4 = 0; c4 < 32; ++c4) {
        float w0 = W2t[(c4 * 4 + 0) * 128 + o];
        float w1 = W2t[(c4 * 4 + 1) * 128 + o];
        float w2 = W2t[(c4 * 4 + 2) * 128 + o];
        float w3 = W2t[(c4 * 4 + 3) * 128 + o];
#pragma unroll
        for (int r = 0; r < 16; ++r) {
            float4 f = *reinterpret_cast<const float4*>(&s_h1[(rh * 16 + r) * 128 + c4 * 4]);
            acc[r] += f.x * w0 + f.y * w1 + f.z * w2 + f.w * w3;
        }
    }
    float ps = 0.f;
#pragma unroll
    for (int r = 0; r < 16; ++r) ps += fmaxf(acc[r], 0.f);
    s_s[rh * 128 + o] = ps;
    __syncthreads();
    if (tid < 128) s_sf[tid] = s_s[tid] + s_s[128 + tid];
    __syncthreads();

    {
        float a = bf1[tid];
        for (int c4 = 0; c4 < 32; ++c4) {
            float4 f = *reinterpret_cast<const float4*>(&s_sf[c4 * 4]);
            a += f.x * F1t[(c4 * 4 + 0) * 256 + tid];
            a += f.y * F1t[(c4 * 4 + 1) * 256 + tid];
            a += f.z * F1t[(c4 * 4 + 2) * 256 + tid];
            a += f.w * F1t[(c4 * 4 + 3) * 256 + tid];
        }
        s_t1[tid] = fmaxf(a, 0.f);
    }
    __syncthreads();

    {
        float a = bf2[tid];
        for (int c4 = 0; c4 < 64; ++c4) {
            float4 f = *reinterpret_cast<const float4*>(&s_t1[c4 * 4]);
            a += f.x * F2t[(c4 * 4 + 0) * 256 + tid];
            a += f.y * F2t[(c4 * 4 + 1) * 256 + tid];
            a += f.z * F2t[(c4 * 4 + 2) * 256 + tid];
            a += f.w * F2t[(c4 * 4 + 3) * 256 + tid];
        }
        outp[(size_t)n * 256 + tid] = a;
    }
}

// ---------------------------------------------------------------------------
extern "C" void kernel_launch(void* const* d_in, const int* in_sizes, int n_in,
                              void* d_out, int out_size, void* d_ws, size_t ws_size,
                              hipStream_t stream)
{
    const int* pos = (const int*)d_in[0];
    const float* rt = (const float*)d_in[1];
    const float* emb = (const float*)d_in[2];
    const float* w1 = (const float*)d_in[3];
    const float* bc1 = (const float*)d_in[4];
    const float* w2 = (const float*)d_in[5];
    const float* bc2 = (const float*)d_in[6];
    const float* w3 = (const float*)d_in[7];
    const float* bc3 = (const float*)d_in[8];
    const float* wr1 = (const float*)d_in[9];
    const float* br1 = (const float*)d_in[10];
    const float* wr2 = (const float*)d_in[11];
    const float* br2 = (const float*)d_in[12];
    const float* wf1 = (const float*)d_in[13];
    const float* bf1 = (const float*)d_in[14];
    const float* wf2 = (const float*)d_in[15];
    const float* bf2 = (const float*)d_in[16];
    float* out = (float*)d_out;
    char* ws = (char*)d_ws;

    prep_weights<<<880, 256, 0, stream>>>(w1, w2, w3, wr1, wr2, wf1, wf2, ws);
    prep_rooms<<<1, 64, 0, stream>>>(rt, ws);

    // largest batch chunk whose X buffer fits the workspace (nc even)
    int nc = 16;
    const int cands[4] = {256, 128, 64, 32};
    for (int k = 0; k < 4; ++k) {
        size_t need = B_CHUNK + (size_t)cands[k] * PERN_BYTES;
        if (need <= ws_size) { nc = cands[k]; break; }
    }

    const short* WALL = (const short*)(ws + B_W1F);
    const unsigned long long* RMASK = (const unsigned long long*)(ws + B_RAUX);
    const float* RINV = (const float*)(ws + B_RINV);
    float* HEAD = (float*)(ws + B_HEAD);
    float* FEAT = (float*)(ws + B_FEAT);
    short* Xc = (short*)(ws + B_CHUNK);

    for (int n0 = 0; n0 < NB; n0 += nc) {
        build_x<<<dim3(21, nc), 256, 0, stream>>>(pos, rt, emb, Xc, n0);
        fused_conv<<<dim3(RR, nc / 2), 256, 0, stream>>>(Xc, WALL, bc1, bc2, bc3,
                                                         pos, RMASK, FEAT, n0);
    }

    mlp_head<<<NB, 256, 0, stream>>>(FEAT, HEAD, RINV, br1, br2, bf1, bf2, out);
}